// Round 9
// baseline (1108.979 us; speedup 1.0000x reference)
//
#include <hip/hip_runtime.h>
#include <cstddef>

#define BB   8
#define TT   1024
#define DDIM 128
#define HH   8
#define DHH  16
#define FF   256
#define BT   (BB * TT)   // 8192

typedef unsigned short u16;
typedef __attribute__((ext_vector_type(8))) short short8;
typedef __attribute__((ext_vector_type(4))) float f32x4;

__device__ __forceinline__ u16 bf(float x) {
  unsigned u = __builtin_bit_cast(unsigned, x);
  u += 0x7fffu + ((u >> 16) & 1u);   // RTN-even
  return (u16)(u >> 16);
}
__device__ __forceinline__ u16 bft(float x) {           // truncate (P in [0,1])
  return (u16)(__builtin_bit_cast(unsigned, x) >> 16);
}
__device__ __forceinline__ float gelu_f(float x) {
  const float t = x * (0.79788456f + 0.03567740814f * x * x);
  return x / (1.0f + __expf(-2.0f * t));
}

// ---------------------------------------------------------------------------
// Software grid barrier (persistent-kernel pattern). Monotonic counter:
// after barrier k the counter equals G*k. Device-scope atomics + fences
// handle cross-XCD coherence (G16).
// ---------------------------------------------------------------------------
__device__ __forceinline__ void gsync(unsigned* cnt, unsigned target) {
  __syncthreads();
  if (threadIdx.x == 0) {
    __threadfence();   // release: drain this block's writes to device scope
    __hip_atomic_fetch_add(cnt, 1u, __ATOMIC_ACQ_REL, __HIP_MEMORY_SCOPE_AGENT);
    while (__hip_atomic_load(cnt, __ATOMIC_ACQUIRE, __HIP_MEMORY_SCOPE_AGENT) < target)
      __builtin_amdgcn_s_sleep(2);
  }
  __syncthreads();
  __threadfence();     // acquire: invalidate stale cache lines for all waves
}

// ---------------------------------------------------------------------------
struct GOp  { const u16* A; const u16* Wt; const float* bias; const float* res;
              float* outF; u16* outB; const float* g; const float* b; };
struct PrepP { const float* W; u16* Wt; };

struct MegaParams {
  GOp qkv[2][6];
  GOp wo[2][2];
  GOp f1[2][2];
  GOp f2[2][2];
  PrepP prep[18];
  const float* x_in; const float* y_in;
  const float* ln1xg; const float* ln1xb; const float* ln1yg; const float* ln1yb;
  u16 *xn, *yn, *qx, *kx, *vx, *qy, *ky, *vy, *ob1, *ob2;
  unsigned* barrier;
};

// LDS union: max(gemm 44.0 KB, attn 28.7 KB, prep 16.6 KB) = 44 KB
struct SMg { u16 As[32][136]; u16 Bs[128][136]; float2 stats[32][2]; };
struct SMa { u16 Ks[2][64][40]; u16 Vt[2][32][72]; u16 Ps[64][72]; };
union __align__(16) SM { SMg g; SMa a; float ptile[64][65]; };

// ---------------------------------------------------------------------------
// prep unit: transpose+convert one 64x64 tile of a fp32 (K,N) weight -> bf16 (N,K)
// ---------------------------------------------------------------------------
__device__ void prep_unit(const MegaParams& P, int u, SM& sm) {
  int idx, tile, K, N;
  if (u < 40)      { idx = u >> 2;               tile = u & 3;        K = 128; N = 128; }
  else if (u < 72) { idx = 10 + ((u - 40) >> 3); tile = (u - 40) & 7; K = 128; N = 256; }
  else             { idx = 14 + ((u - 72) >> 3); tile = (u - 72) & 7; K = 256; N = 128; }
  const int n0 = (N == 256) ? (tile & 3) * 64 : (tile & 1) * 64;
  const int k0 = (N == 256) ? (tile >> 2) * 64 : (tile >> 1) * 64;
  const PrepP pp = P.prep[idx];
  const int tid = threadIdx.x;
  #pragma unroll
  for (int t = tid; t < 1024; t += 256) {
    const int kk = t >> 4, nn4 = (t & 15) << 2;
    float4 v = *(const float4*)(pp.W + (size_t)(k0 + kk) * N + n0 + nn4);
    sm.ptile[nn4 + 0][kk] = v.x; sm.ptile[nn4 + 1][kk] = v.y;
    sm.ptile[nn4 + 2][kk] = v.z; sm.ptile[nn4 + 3][kk] = v.w;
  }
  __syncthreads();
  #pragma unroll
  for (int t = tid; t < 1024; t += 256) {
    const int nn = t >> 4, kk4 = (t & 15) << 2;
    ushort4 o;
    o.x = bf(sm.ptile[nn][kk4 + 0]); o.y = bf(sm.ptile[nn][kk4 + 1]);
    o.z = bf(sm.ptile[nn][kk4 + 2]); o.w = bf(sm.ptile[nn][kk4 + 3]);
    *(ushort4*)(pp.Wt + (size_t)(n0 + nn) * K + k0 + kk4) = o;
  }
  __syncthreads();   // guard ptile reuse by next unit
}

// ---------------------------------------------------------------------------
// LN0 unit: 4 rows of layer-0 LN1 (fp32 in -> bf16 out)
// ---------------------------------------------------------------------------
__device__ void ln0_unit(const MegaParams& P, int u2) {
  const int which = u2 & 1;
  const int row   = (u2 >> 1) * 4 + (threadIdx.x >> 6);
  const int lane  = threadIdx.x & 63;
  const float* in = which ? P.y_in : P.x_in;
  const float* g  = which ? P.ln1yg : P.ln1xg;
  const float* b  = which ? P.ln1yb : P.ln1xb;
  u16* out        = which ? P.yn : P.xn;

  float2 v = *(const float2*)(in + (size_t)row * DDIM + lane * 2);
  float s  = v.x + v.y;
  float sq = v.x * v.x + v.y * v.y;
  #pragma unroll
  for (int off = 32; off >= 1; off >>= 1) {
    s  += __shfl_xor(s, off);
    sq += __shfl_xor(sq, off);
  }
  const float mean = s * (1.0f / DDIM);
  const float var  = sq * (1.0f / DDIM) - mean * mean;
  const float r    = rsqrtf(var + 1e-5f);
  float2 gg = *(const float2*)(g + lane * 2);
  float2 bb = *(const float2*)(b + lane * 2);
  ushort2 o;
  o.x = bf((v.x - mean) * r * gg.x + bb.x);
  o.y = bf((v.y - mean) * r * gg.y + bb.y);
  *(ushort2*)(out + (size_t)row * DDIM + lane * 2) = o;
}

// ---------------------------------------------------------------------------
// 32x128 bf16 MFMA GEMM tile, BK=128 single-barrier staging; fused epilogue.
// ---------------------------------------------------------------------------
__device__ void gemm_tile(const GOp op, const int K, const int N, const int gelu,
                          const int ln, const int m0, const int n0, SM& sm) {
  const int tid  = threadIdx.x;
  const int w    = tid >> 6;
  const int lane = tid & 63;
  const int l15  = lane & 15;
  const int quad = lane >> 4;
  const int wr = w & 1, wc = w >> 1;

  f32x4 acc[4];
  #pragma unroll
  for (int j = 0; j < 4; ++j) acc[j] = {0.f, 0.f, 0.f, 0.f};

  for (int k0 = 0; k0 < K; k0 += 128) {
    #pragma unroll
    for (int t = tid; t < 512; t += 256) {
      const int r = t >> 4, g8 = (t & 15) << 3;
      *(short8*)&sm.g.As[r][g8] = *(const short8*)(op.A + (size_t)(m0 + r) * K + k0 + g8);
    }
    #pragma unroll
    for (int t = tid; t < 2048; t += 256) {
      const int r = t >> 4, g8 = (t & 15) << 3;
      *(short8*)&sm.g.Bs[r][g8] = *(const short8*)(op.Wt + (size_t)(n0 + r) * K + k0 + g8);
    }
    __syncthreads();
    #pragma unroll
    for (int ks = 0; ks < 4; ++ks) {
      const short8 ar = *(const short8*)&sm.g.As[wr * 16 + l15][ks * 32 + quad * 8];
      #pragma unroll
      for (int j = 0; j < 4; ++j) {
        const short8 br = *(const short8*)&sm.g.Bs[wc * 64 + j * 16 + l15][ks * 32 + quad * 8];
        acc[j] = __builtin_amdgcn_mfma_f32_16x16x32_bf16(ar, br, acc[j], 0, 0, 0);
      }
    }
    __syncthreads();   // guard As/Bs reuse (next k0 stage or next unit)
  }

  // ---- epilogue: bias / gelu / res, raw fp32 store ----
  #pragma unroll
  for (int j = 0; j < 4; ++j) {
    const int n = n0 + wc * 64 + j * 16 + l15;
    const float bias_v = op.bias ? op.bias[n] : 0.f;
    #pragma unroll
    for (int reg = 0; reg < 4; ++reg) {
      const int m = m0 + wr * 16 + quad * 4 + reg;
      float v = acc[j][reg] + bias_v;
      if (gelu) v = gelu_f(v);
      if (op.res) v += op.res[(size_t)m * N + n];
      acc[j][reg] = v;
      if (op.outF) op.outF[(size_t)m * N + n] = v;
    }
  }

  if (!ln) {
    if (op.outB) {
      #pragma unroll
      for (int j = 0; j < 4; ++j) {
        const int n = n0 + wc * 64 + j * 16 + l15;
        #pragma unroll
        for (int reg = 0; reg < 4; ++reg) {
          const int m = m0 + wr * 16 + quad * 4 + reg;
          op.outB[(size_t)m * N + n] = bf(acc[j][reg]);
        }
      }
    }
    return;
  }

  // ---- fused LayerNorm (N==128, n0==0: both col-halves in this block) ----
  #pragma unroll
  for (int reg = 0; reg < 4; ++reg) {
    float s = 0.f, q = 0.f;
    #pragma unroll
    for (int j = 0; j < 4; ++j) { const float v = acc[j][reg]; s += v; q += v * v; }
    #pragma unroll
    for (int off = 8; off >= 1; off >>= 1) {
      s += __shfl_xor(s, off, 16);
      q += __shfl_xor(q, off, 16);
    }
    if (l15 == 0) sm.g.stats[wr * 16 + quad * 4 + reg][wc] = make_float2(s, q);
  }
  __syncthreads();
  #pragma unroll
  for (int reg = 0; reg < 4; ++reg) {
    const int mloc = wr * 16 + quad * 4 + reg;
    const float2 s0 = sm.g.stats[mloc][0], s1 = sm.g.stats[mloc][1];
    const float mean = (s0.x + s1.x) * (1.0f / 128.f);
    const float var  = (s0.y + s1.y) * (1.0f / 128.f) - mean * mean;
    const float r    = rsqrtf(var + 1e-5f);
    #pragma unroll
    for (int j = 0; j < 4; ++j) {
      const int n = wc * 64 + j * 16 + l15;
      op.outB[(size_t)(m0 + mloc) * 128 + n] =
          bf((acc[j][reg] - mean) * r * op.g[n] + op.b[n]);
    }
  }
  __syncthreads();   // guard stats reuse by next unit
}

// ---------------------------------------------------------------------------
// Flash attention unit: 64 q-rows (wave owns 16), dbuf K/V, 1 barrier / tile.
// ---------------------------------------------------------------------------
__device__ void attn_unit(const MegaParams& P, int t0, int bh, SM& sm) {
  const int b = bh >> 3, h = bh & 7;
  const size_t base = (size_t)b * TT * DDIM + h * DHH;
  const int tid  = threadIdx.x;
  const int w    = tid >> 6;
  const int lane = tid & 63;
  const int l15  = lane & 15;
  const int quad = lane >> 4;

  const u16* qp = (quad < 2) ? P.qx : P.qy;
  const int dq = (quad & 1) * 8;
  const short8 qa = *(const short8*)(qp + base + (size_t)(t0 + w * 16 + l15) * DDIM + dq);

  f32x4 Of0 = {0.f, 0.f, 0.f, 0.f};
  f32x4 Of1 = {0.f, 0.f, 0.f, 0.f};
  float l_i[4] = {0.f, 0.f, 0.f, 0.f};

  const int ks_s = tid >> 2, ks_c = tid & 3;
  const u16* ks_p = (ks_c < 2) ? P.kx : P.ky;
  const int ks_d8 = (ks_c & 1) * 8;
  const int ks_col = (ks_c < 2 ? 0 : 16) + ks_d8;

  const u16* vs_p = (w < 2) ? P.vx : P.vy;
  const int vs_cc = (w & 1) * 8;
  const int vs_cb = (w < 2 ? 0 : 16) + vs_cc;

  auto stageKV = [&](int kt, int buf) {
    const int s0_ = kt * 64;
    *(short8*)&sm.a.Ks[buf][ks_s][ks_col] =
        *(const short8*)(ks_p + base + (size_t)(s0_ + ks_s) * DDIM + ks_d8);
    const short8 v8 =
        *(const short8*)(vs_p + base + (size_t)(s0_ + lane) * DDIM + vs_cc);
    #pragma unroll
    for (int e = 0; e < 8; ++e) sm.a.Vt[buf][vs_cb + e][lane] = (u16)v8[e];
  };

  stageKV(0, 0);

  for (int kt = 0; kt < TT / 64; ++kt) {
    const int buf = kt & 1;
    __syncthreads();
    if (kt + 1 < TT / 64) stageKV(kt + 1, buf ^ 1);

    f32x4 Sf[4];
    #pragma unroll
    for (int t = 0; t < 4; ++t) {
      short8 kb = *(const short8*)&sm.a.Ks[buf][t * 16 + l15][quad * 8];
      f32x4 z = {0.f, 0.f, 0.f, 0.f};
      Sf[t] = __builtin_amdgcn_mfma_f32_16x16x32_bf16(qa, kb, z, 0, 0, 0);
    }

    #pragma unroll
    for (int reg = 0; reg < 4; ++reg) {
      const float p0 = exp2f(Sf[0][reg] * 0.18033688011112042f);
      const float p1 = exp2f(Sf[1][reg] * 0.18033688011112042f);
      const float p2 = exp2f(Sf[2][reg] * 0.18033688011112042f);
      const float p3 = exp2f(Sf[3][reg] * 0.18033688011112042f);
      l_i[reg] += p0 + p1 + p2 + p3;
      const int q = w * 16 + quad * 4 + reg;
      sm.a.Ps[q][l15]      = bft(p0);
      sm.a.Ps[q][16 + l15] = bft(p1);
      sm.a.Ps[q][32 + l15] = bft(p2);
      sm.a.Ps[q][48 + l15] = bft(p3);
    }

    #pragma unroll
    for (int sh = 0; sh < 2; ++sh) {
      short8 pa  = *(const short8*)&sm.a.Ps[w * 16 + l15][sh * 32 + quad * 8];
      short8 vb0 = *(const short8*)&sm.a.Vt[buf][l15][sh * 32 + quad * 8];
      short8 vb1 = *(const short8*)&sm.a.Vt[buf][16 + l15][sh * 32 + quad * 8];
      Of0 = __builtin_amdgcn_mfma_f32_16x16x32_bf16(pa, vb0, Of0, 0, 0, 0);
      Of1 = __builtin_amdgcn_mfma_f32_16x16x32_bf16(pa, vb1, Of1, 0, 0, 0);
    }
  }

  #pragma unroll
  for (int reg = 0; reg < 4; ++reg) {
    float l = l_i[reg];
    #pragma unroll
    for (int off = 8; off >= 1; off >>= 1) l += __shfl_xor(l, off, 16);
    const float inv = 1.0f / l;
    const size_t r = base + (size_t)(t0 + w * 16 + quad * 4 + reg) * DDIM + l15;
    P.ob1[r] = bf(Of0[reg] * inv);
    P.ob2[r] = bf(Of1[reg] * inv);
  }
  __syncthreads();   // guard Ks/Vt/Ps reuse by next unit
}

// ---------------------------------------------------------------------------
// Persistent mega-kernel (plain launch, software grid barrier).
// Grid MUST be <= co-resident capacity: 512 blocks @ 2 blocks/CU x 256 CUs.
// ---------------------------------------------------------------------------
__global__ __launch_bounds__(256, 2) void mega_k(MegaParams P) {
  __shared__ SM sm;
  const int G = (int)gridDim.x;
  unsigned* cnt = P.barrier;
  unsigned ep = 0;

  // stage 0: weight prep (104 tiles) + layer-0 LN1 (4096 row-quads)
  for (int u = blockIdx.x; u < 104 + 4096; u += G) {
    if (u < 104) prep_unit(P, u, sm);
    else         ln0_unit(P, u - 104);
  }
  ep += G; gsync(cnt, ep);

  for (int l = 0; l < 2; ++l) {
    // QKV: 6 ops x 256 row-tiles
    for (int u = blockIdx.x; u < 1536; u += G)
      gemm_tile(P.qkv[l][u >> 8], 128, 128, 0, 0, (u & 255) * 32, 0, sm);
    ep += G; gsync(cnt, ep);

    // attention: 16 q-tiles x 64 bh
    for (int u = blockIdx.x; u < 1024; u += G)
      attn_unit(P, (u & 15) * 64, u >> 4, sm);
    ep += G; gsync(cnt, ep);

    // Wo + residual + LN2: 2 branches x 256 row-tiles
    for (int u = blockIdx.x; u < 512; u += G)
      gemm_tile(P.wo[l][u >> 8], 128, 128, 0, 1, (u & 255) * 32, 0, sm);
    ep += G; gsync(cnt, ep);

    // FFN1 + gelu: 2 branches x 256 rows x 2 col-tiles
    for (int u = blockIdx.x; u < 1024; u += G) {
      const int r = u >> 1;
      gemm_tile(P.f1[l][u & 1], 128, 256, 1, 0, (r & 255) * 32, (r >> 8) * 128, sm);
    }
    ep += G; gsync(cnt, ep);

    // FFN2 + residual (+ next-layer LN1 when l==0)
    for (int u = blockIdx.x; u < 512; u += G)
      gemm_tile(P.f2[l][u & 1], 256, 128, 0, (l == 0) ? 1 : 0, (u >> 1) * 32, 0, sm);
    if (l == 0) { ep += G; gsync(cnt, ep); }
  }
}

// ---------------------------------------------------------------------------
extern "C" void kernel_launch(void* const* d_in, const int* in_sizes, int n_in,
                              void* d_out, int out_size, void* d_ws, size_t ws_size,
                              hipStream_t stream) {
  const float* x_in  = (const float*)d_in[0];
  const float* y_in  = (const float*)d_in[1];
  const float* Wq    = (const float*)d_in[2];
  const float* Wk    = (const float*)d_in[3];
  const float* Wv    = (const float*)d_in[4];
  const float* Wox   = (const float*)d_in[5];
  const float* box   = (const float*)d_in[6];
  const float* Woy   = (const float*)d_in[7];
  const float* boy   = (const float*)d_in[8];
  const float* ln1xg = (const float*)d_in[9];
  const float* ln1xb = (const float*)d_in[10];
  const float* ln1yg = (const float*)d_in[11];
  const float* ln1yb = (const float*)d_in[12];
  const float* ln2xg = (const float*)d_in[13];
  const float* ln2xb = (const float*)d_in[14];
  const float* ln2yg = (const float*)d_in[15];
  const float* ln2yb = (const float*)d_in[16];
  const float* fxw1  = (const float*)d_in[17];
  const float* fxb1  = (const float*)d_in[18];
  const float* fxw2  = (const float*)d_in[19];
  const float* fxb2  = (const float*)d_in[20];
  const float* fyw1  = (const float*)d_in[21];
  const float* fyb1  = (const float*)d_in[22];
  const float* fyw2  = (const float*)d_in[23];
  const float* fyb2  = (const float*)d_in[24];

  const size_t S = (size_t)BT * DDIM;  // 1,048,576 elems
  float* X = (float*)d_out;
  float* Y = X + S;

  char* wsb = (char*)d_ws;
  auto carve = [&](size_t bytes) { char* p = wsb; wsb += (bytes + 255) & ~(size_t)255; return p; };
  unsigned* barrier = (unsigned*)carve(256);
  u16* xn  = (u16*)carve(S * 2);
  u16* yn  = (u16*)carve(S * 2);
  u16* qx  = (u16*)carve(S * 2);
  u16* kx  = (u16*)carve(S * 2);
  u16* vx  = (u16*)carve(S * 2);
  u16* qy  = (u16*)carve(S * 2);
  u16* ky  = (u16*)carve(S * 2);
  u16* vy  = (u16*)carve(S * 2);
  u16* ob1 = (u16*)carve(S * 2);
  u16* ob2 = (u16*)carve(S * 2);
  u16* hx  = (u16*)carve(2 * S * 2);
  u16* hy  = (u16*)carve(2 * S * 2);
  u16* WqT[2], *WkT[2], *WvT[2], *WoxT[2], *WoyT[2];
  u16* f1xT[2], *f1yT[2], *f2xT[2], *f2yT[2];
  for (int l = 0; l < 2; ++l) {
    WqT[l]  = (u16*)carve(16384 * 2);
    WkT[l]  = (u16*)carve(16384 * 2);
    WvT[l]  = (u16*)carve(16384 * 2);
    WoxT[l] = (u16*)carve(16384 * 2);
    WoyT[l] = (u16*)carve(16384 * 2);
    f1xT[l] = (u16*)carve(32768 * 2);
    f1yT[l] = (u16*)carve(32768 * 2);
    f2xT[l] = (u16*)carve(32768 * 2);
    f2yT[l] = (u16*)carve(32768 * 2);
  }

  MegaParams P;
  // prep table: [0..9] K128N128, [10..13] K128N256 (f1), [14..17] K256N128 (f2)
  {
    int pi = 0;
    for (int l = 0; l < 2; ++l) {
      P.prep[pi++] = {Wq  + (size_t)l * 16384, WqT[l]};
      P.prep[pi++] = {Wk  + (size_t)l * 16384, WkT[l]};
      P.prep[pi++] = {Wv  + (size_t)l * 16384, WvT[l]};
      P.prep[pi++] = {Wox + (size_t)l * 16384, WoxT[l]};
      P.prep[pi++] = {Woy + (size_t)l * 16384, WoyT[l]};
    }
    for (int l = 0; l < 2; ++l) {
      P.prep[pi++] = {fxw1 + (size_t)l * 32768, f1xT[l]};
      P.prep[pi++] = {fyw1 + (size_t)l * 32768, f1yT[l]};
    }
    for (int l = 0; l < 2; ++l) {
      P.prep[pi++] = {fxw2 + (size_t)l * 32768, f2xT[l]};
      P.prep[pi++] = {fyw2 + (size_t)l * 32768, f2yT[l]};
    }
  }
  for (int l = 0; l < 2; ++l) {
    const size_t bo  = (size_t)l * DDIM;
    const size_t fbo = (size_t)l * FF;
    P.qkv[l][0] = {yn, WqT[l], nullptr, nullptr, nullptr, qx, nullptr, nullptr};
    P.qkv[l][1] = {xn, WkT[l], nullptr, nullptr, nullptr, kx, nullptr, nullptr};
    P.qkv[l][2] = {xn, WvT[l], nullptr, nullptr, nullptr, vx, nullptr, nullptr};
    P.qkv[l][3] = {xn, WqT[l], nullptr, nullptr, nullptr, qy, nullptr, nullptr};
    P.qkv[l][4] = {yn, WkT[l], nullptr, nullptr, nullptr, ky, nullptr, nullptr};
    P.qkv[l][5] = {yn, WvT[l], nullptr, nullptr, nullptr, vy, nullptr, nullptr};
    P.wo[l][0] = {ob1, WoxT[l], box + bo, (l == 0) ? x_in : X, X, xn, ln2xg + bo, ln2xb + bo};
    P.wo[l][1] = {ob2, WoyT[l], boy + bo, (l == 0) ? y_in : Y, Y, yn, ln2yg + bo, ln2yb + bo};
    P.f1[l][0] = {xn, f1xT[l], fxb1 + fbo, nullptr, nullptr, hx, nullptr, nullptr};
    P.f1[l][1] = {yn, f1yT[l], fyb1 + fbo, nullptr, nullptr, hy, nullptr, nullptr};
    if (l == 0) {
      P.f2[l][0] = {hx, f2xT[l], fxb2 + bo, X, X, xn, ln1xg + DDIM, ln1xb + DDIM};
      P.f2[l][1] = {hy, f2yT[l], fyb2 + bo, Y, Y, yn, ln1yg + DDIM, ln1yb + DDIM};
    } else {
      P.f2[l][0] = {hx, f2xT[l], fxb2 + bo, X, X, nullptr, nullptr, nullptr};
      P.f2[l][1] = {hy, f2yT[l], fyb2 + bo, Y, Y, nullptr, nullptr, nullptr};
    }
  }
  P.x_in = x_in; P.y_in = y_in;
  P.ln1xg = ln1xg; P.ln1xb = ln1xb; P.ln1yg = ln1yg; P.ln1yb = ln1yb;
  P.xn = xn; P.yn = yn;
  P.qx = qx; P.kx = kx; P.vx = vx; P.qy = qy; P.ky = ky; P.vy = vy;
  P.ob1 = ob1; P.ob2 = ob2;
  P.barrier = barrier;

  hipMemsetAsync(barrier, 0, 256, stream);
  mega_k<<<dim3(512), dim3(256), 0, stream>>>(P);
}

// Round 10
// 270.884 us; speedup vs baseline: 4.0939x; 4.0939x over previous
//
#include <hip/hip_runtime.h>
#include <cstddef>

#define BB   8
#define TT   1024
#define DDIM 128
#define HH   8
#define DHH  16
#define FF   256
#define BT   (BB * TT)   // 8192

typedef unsigned short u16;
typedef __attribute__((ext_vector_type(8))) short short8;
typedef __attribute__((ext_vector_type(4))) float f32x4;

__device__ __forceinline__ u16 bf(float x) {
  unsigned u = __builtin_bit_cast(unsigned, x);
  u += 0x7fffu + ((u >> 16) & 1u);   // RTN-even
  return (u16)(u >> 16);
}
__device__ __forceinline__ u16 bft(float x) {           // truncate (P in [0,1])
  return (u16)(__builtin_bit_cast(unsigned, x) >> 16);
}
__device__ __forceinline__ float gelu_f(float x) {
  const float t = x * (0.79788456f + 0.03567740814f * x * x);
  return x / (1.0f + __expf(-2.0f * t));
}

// ---------------------------------------------------------------------------
// Weight prep: fp32 (K,N) -> bf16 (N,K)  (transpose + convert), 18 matrices.
// ---------------------------------------------------------------------------
struct PrepP { const float* W; u16* Wt; int K; int N; };
struct PrepArgs { PrepP p[18]; };

__global__ __launch_bounds__(256) void prep_k(PrepArgs a) {
  const PrepP pp = a.p[blockIdx.z];
  const int n0 = blockIdx.x * 64, k0 = blockIdx.y * 64;
  if (n0 >= pp.N || k0 >= pp.K) return;
  __shared__ float tile[64][65];
  const int tid = threadIdx.x;
  #pragma unroll
  for (int t = tid; t < 1024; t += 256) {
    const int kk = t >> 4, nn4 = (t & 15) << 2;
    float4 v = *(const float4*)(pp.W + (size_t)(k0 + kk) * pp.N + n0 + nn4);
    tile[nn4 + 0][kk] = v.x; tile[nn4 + 1][kk] = v.y;
    tile[nn4 + 2][kk] = v.z; tile[nn4 + 3][kk] = v.w;
  }
  __syncthreads();
  #pragma unroll
  for (int t = tid; t < 1024; t += 256) {
    const int nn = t >> 4, kk4 = (t & 15) << 2;
    ushort4 o;
    o.x = bf(tile[nn][kk4 + 0]); o.y = bf(tile[nn][kk4 + 1]);
    o.z = bf(tile[nn][kk4 + 2]); o.w = bf(tile[nn][kk4 + 3]);
    *(ushort4*)(pp.Wt + (size_t)(n0 + nn) * pp.K + k0 + kk4) = o;
  }
}

// ---------------------------------------------------------------------------
// Standalone LN (layer-0 LN1 only): fp32 in -> bf16 out. 4 rows / 256-thr block.
// ---------------------------------------------------------------------------
__global__ __launch_bounds__(256) void ln0_k(const float* __restrict__ X,
                                             const float* __restrict__ Y,
                                             const float* __restrict__ gx,
                                             const float* __restrict__ bx,
                                             const float* __restrict__ gy,
                                             const float* __restrict__ by,
                                             u16* __restrict__ ox,
                                             u16* __restrict__ oy) {
  const int which = blockIdx.y;
  const float* in = which ? Y : X;
  const float* g  = which ? gy : gx;
  const float* b  = which ? by : bx;
  u16* out        = which ? oy : ox;
  const int row  = blockIdx.x * 4 + (threadIdx.x >> 6);
  const int lane = threadIdx.x & 63;

  float2 v = *(const float2*)(in + (size_t)row * DDIM + lane * 2);
  float s  = v.x + v.y;
  float sq = v.x * v.x + v.y * v.y;
  #pragma unroll
  for (int off = 32; off >= 1; off >>= 1) {
    s  += __shfl_xor(s, off);
    sq += __shfl_xor(sq, off);
  }
  const float mean = s * (1.0f / DDIM);
  const float var  = sq * (1.0f / DDIM) - mean * mean;
  const float r    = rsqrtf(var + 1e-5f);
  float2 gg = *(const float2*)(g + lane * 2);
  float2 bb = *(const float2*)(b + lane * 2);
  ushort2 o;
  o.x = bf((v.x - mean) * r * gg.x + bb.x);
  o.y = bf((v.y - mean) * r * gg.y + bb.y);
  *(ushort2*)(out + (size_t)row * DDIM + lane * 2) = o;
}

// ---------------------------------------------------------------------------
// bf16 MFMA GEMM, 32x128 tile, 256 threads = 4 waves (wr = row-half of 16,
// wc = col-half of 64). BK=128 single-barrier staging. Fused epilogue:
// bias / +res fp32 / bf16 out / per-row LayerNorm (ln requires N==128).
// Used for QKV and Wo.
// ---------------------------------------------------------------------------
struct GemmP { const u16* A; const u16* Wt; const float* bias; const float* res;
               float* outF; u16* outB; const float* g; const float* b; };
struct GemmArgs { GemmP p[6]; int ln; };

__global__ __launch_bounds__(256) void gemmf_k(GemmArgs a) {
  const GemmP pp = a.p[blockIdx.z];
  const int m0 = blockIdx.y * 32;
  __shared__ __align__(16) u16 As[32][136];
  __shared__ __align__(16) u16 Bs[128][136];
  __shared__ float2 stats[32][2];
  const int tid  = threadIdx.x;
  const int w    = tid >> 6;
  const int lane = tid & 63;
  const int l15  = lane & 15;
  const int quad = lane >> 4;
  const int wr = w & 1, wc = w >> 1;

  f32x4 acc[4];
  #pragma unroll
  for (int j = 0; j < 4; ++j) acc[j] = {0.f, 0.f, 0.f, 0.f};

  #pragma unroll
  for (int t = tid; t < 512; t += 256) {
    const int r = t >> 4, g8 = (t & 15) << 3;
    *(short8*)&As[r][g8] = *(const short8*)(pp.A + (size_t)(m0 + r) * 128 + g8);
  }
  #pragma unroll
  for (int t = tid; t < 2048; t += 256) {
    const int r = t >> 4, g8 = (t & 15) << 3;
    *(short8*)&Bs[r][g8] = *(const short8*)(pp.Wt + (size_t)r * 128 + g8);
  }
  __syncthreads();
  #pragma unroll
  for (int ks = 0; ks < 4; ++ks) {
    const short8 ar = *(const short8*)&As[wr * 16 + l15][ks * 32 + quad * 8];
    #pragma unroll
    for (int j = 0; j < 4; ++j) {
      const short8 br = *(const short8*)&Bs[wc * 64 + j * 16 + l15][ks * 32 + quad * 8];
      acc[j] = __builtin_amdgcn_mfma_f32_16x16x32_bf16(ar, br, acc[j], 0, 0, 0);
    }
  }

  // ---- epilogue: bias / res, raw fp32 store ----
  #pragma unroll
  for (int j = 0; j < 4; ++j) {
    const int n = wc * 64 + j * 16 + l15;
    const float bias_v = pp.bias ? pp.bias[n] : 0.f;
    #pragma unroll
    for (int reg = 0; reg < 4; ++reg) {
      const int m = m0 + wr * 16 + quad * 4 + reg;
      float v = acc[j][reg] + bias_v;
      if (pp.res) v += pp.res[(size_t)m * 128 + n];
      acc[j][reg] = v;
      if (pp.outF) pp.outF[(size_t)m * 128 + n] = v;
    }
  }

  if (!a.ln) {
    #pragma unroll
    for (int j = 0; j < 4; ++j) {
      const int n = wc * 64 + j * 16 + l15;
      #pragma unroll
      for (int reg = 0; reg < 4; ++reg) {
        const int m = m0 + wr * 16 + quad * 4 + reg;
        pp.outB[(size_t)m * 128 + n] = bf(acc[j][reg]);
      }
    }
    return;
  }

  // ---- fused LayerNorm ----
  #pragma unroll
  for (int reg = 0; reg < 4; ++reg) {
    float s = 0.f, q = 0.f;
    #pragma unroll
    for (int j = 0; j < 4; ++j) { const float v = acc[j][reg]; s += v; q += v * v; }
    #pragma unroll
    for (int off = 8; off >= 1; off >>= 1) {
      s += __shfl_xor(s, off, 16);
      q += __shfl_xor(q, off, 16);
    }
    if (l15 == 0) stats[wr * 16 + quad * 4 + reg][wc] = make_float2(s, q);
  }
  __syncthreads();
  #pragma unroll
  for (int reg = 0; reg < 4; ++reg) {
    const int mloc = wr * 16 + quad * 4 + reg;
    const float2 s0 = stats[mloc][0], s1 = stats[mloc][1];
    const float mean = (s0.x + s1.x) * (1.0f / 128.f);
    const float var  = (s0.y + s1.y) * (1.0f / 128.f) - mean * mean;
    const float r    = rsqrtf(var + 1e-5f);
    #pragma unroll
    for (int j = 0; j < 4; ++j) {
      const int n = wc * 64 + j * 16 + l15;
      pp.outB[(size_t)(m0 + mloc) * 128 + n] =
          bf((acc[j][reg] - mean) * r * pp.g[n] + pp.b[n]);
    }
  }
}

// ---------------------------------------------------------------------------
// Fused FFN: out = gelu(A@W1+b1)@W2 + b2 [+res] per 32-row tile, h in LDS.
// W1t: (256,K=128) bf16; W2t: (128,K=256) bf16.
// ---------------------------------------------------------------------------
struct FfnP { const u16* A; const u16* W1t; const float* b1;
              const u16* W2t; const float* b2; const float* res;
              float* outF; u16* outB; const float* g; const float* b; };
struct FfnArgs { FfnP p[2]; int ln; };

__global__ __launch_bounds__(256) void ffn_k(FfnArgs a) {
  const FfnP pp = a.p[blockIdx.y];
  const int m0 = blockIdx.x * 32;
  __shared__ __align__(16) u16 As[32][136];
  __shared__ __align__(16) u16 Bs[128][136];
  __shared__ __align__(16) u16 Hs[32][264];
  __shared__ float2 stats[32][2];
  const int tid  = threadIdx.x;
  const int w    = tid >> 6;
  const int lane = tid & 63;
  const int l15  = lane & 15;
  const int quad = lane >> 4;
  const int wr = w & 1, wc = w >> 1;

  // stage A (32x128) once
  #pragma unroll
  for (int t = tid; t < 512; t += 256) {
    const int r = t >> 4, g8 = (t & 15) << 3;
    *(short8*)&As[r][g8] = *(const short8*)(pp.A + (size_t)(m0 + r) * 128 + g8);
  }

  // ---- FFN1: h = gelu(A@W1+b1), built in LDS in two 128-col halves ----
  for (int nh = 0; nh < 2; ++nh) {
    #pragma unroll
    for (int t = tid; t < 2048; t += 256) {
      const int r = t >> 4, g8 = (t & 15) << 3;
      *(short8*)&Bs[r][g8] = *(const short8*)(pp.W1t + (size_t)(nh * 128 + r) * 128 + g8);
    }
    __syncthreads();
    f32x4 acc[4];
    #pragma unroll
    for (int j = 0; j < 4; ++j) acc[j] = {0.f, 0.f, 0.f, 0.f};
    #pragma unroll
    for (int ks = 0; ks < 4; ++ks) {
      const short8 ar = *(const short8*)&As[wr * 16 + l15][ks * 32 + quad * 8];
      #pragma unroll
      for (int j = 0; j < 4; ++j) {
        const short8 br = *(const short8*)&Bs[wc * 64 + j * 16 + l15][ks * 32 + quad * 8];
        acc[j] = __builtin_amdgcn_mfma_f32_16x16x32_bf16(ar, br, acc[j], 0, 0, 0);
      }
    }
    #pragma unroll
    for (int j = 0; j < 4; ++j) {
      const int n = wc * 64 + j * 16 + l15;
      const float bias_v = pp.b1[nh * 128 + n];
      #pragma unroll
      for (int reg = 0; reg < 4; ++reg) {
        const int mloc = wr * 16 + quad * 4 + reg;
        Hs[mloc][nh * 128 + n] = bf(gelu_f(acc[j][reg] + bias_v));
      }
    }
    __syncthreads();   // Bs reads done + Hs half visible
  }

  // ---- FFN2: out = h@W2 + b2 (+res), accumulate over two K-halves ----
  f32x4 acc2[4];
  #pragma unroll
  for (int j = 0; j < 4; ++j) acc2[j] = {0.f, 0.f, 0.f, 0.f};
  for (int kh = 0; kh < 2; ++kh) {
    #pragma unroll
    for (int t = tid; t < 2048; t += 256) {
      const int r = t >> 4, g8 = (t & 15) << 3;
      *(short8*)&Bs[r][g8] = *(const short8*)(pp.W2t + (size_t)r * 256 + kh * 128 + g8);
    }
    __syncthreads();
    #pragma unroll
    for (int ks = 0; ks < 4; ++ks) {
      const short8 ar = *(const short8*)&Hs[wr * 16 + l15][kh * 128 + ks * 32 + quad * 8];
      #pragma unroll
      for (int j = 0; j < 4; ++j) {
        const short8 br = *(const short8*)&Bs[wc * 64 + j * 16 + l15][ks * 32 + quad * 8];
        acc2[j] = __builtin_amdgcn_mfma_f32_16x16x32_bf16(ar, br, acc2[j], 0, 0, 0);
      }
    }
    __syncthreads();   // guard Bs restage
  }

  // ---- epilogue: bias + res, fp32 out, optional LN -> outB ----
  #pragma unroll
  for (int j = 0; j < 4; ++j) {
    const int n = wc * 64 + j * 16 + l15;
    const float bias_v = pp.b2[n];
    #pragma unroll
    for (int reg = 0; reg < 4; ++reg) {
      const int m = m0 + wr * 16 + quad * 4 + reg;
      float v = acc2[j][reg] + bias_v + pp.res[(size_t)m * 128 + n];
      acc2[j][reg] = v;
      pp.outF[(size_t)m * 128 + n] = v;
    }
  }
  if (!a.ln) return;
  #pragma unroll
  for (int reg = 0; reg < 4; ++reg) {
    float s = 0.f, q = 0.f;
    #pragma unroll
    for (int j = 0; j < 4; ++j) { const float v = acc2[j][reg]; s += v; q += v * v; }
    #pragma unroll
    for (int off = 8; off >= 1; off >>= 1) {
      s += __shfl_xor(s, off, 16);
      q += __shfl_xor(q, off, 16);
    }
    if (l15 == 0) stats[wr * 16 + quad * 4 + reg][wc] = make_float2(s, q);
  }
  __syncthreads();
  #pragma unroll
  for (int reg = 0; reg < 4; ++reg) {
    const int mloc = wr * 16 + quad * 4 + reg;
    const float2 s0 = stats[mloc][0], s1 = stats[mloc][1];
    const float mean = (s0.x + s1.x) * (1.0f / 128.f);
    const float var  = (s0.y + s1.y) * (1.0f / 128.f) - mean * mean;
    const float r    = rsqrtf(var + 1e-5f);
    #pragma unroll
    for (int j = 0; j < 4; ++j) {
      const int n = wc * 64 + j * 16 + l15;
      pp.outB[(size_t)(m0 + mloc) * 128 + n] =
          bf((acc2[j][reg] - mean) * r * pp.g[n] + pp.b[n]);
    }
  }
}

// ---------------------------------------------------------------------------
// MFMA flash attention (shared softmax). 64 q-rows / block (wave owns 16),
// 128-KEY tiles (8 iters), double-buffered K/V, ONE barrier per tile.
// ---------------------------------------------------------------------------
__global__ __launch_bounds__(256) void attn_k(const u16* __restrict__ qx,
                                              const u16* __restrict__ kx,
                                              const u16* __restrict__ vx,
                                              const u16* __restrict__ qy,
                                              const u16* __restrict__ ky,
                                              const u16* __restrict__ vy,
                                              u16* __restrict__ o1,
                                              u16* __restrict__ o2) {
  const int t0 = blockIdx.x * 64;
  const int bh = blockIdx.y;
  const int b = bh >> 3, h = bh & 7;
  const size_t base = (size_t)b * TT * DDIM + h * DHH;

  __shared__ __align__(16) u16 Ks[2][128][40];  // [buf][s][d0..31]
  __shared__ __align__(16) u16 Vt[2][32][136];  // [buf][c][s0..127]
  __shared__ __align__(16) u16 Ps[64][136];     // [q][s0..127] (wave-private rows)

  const int tid  = threadIdx.x;
  const int w    = tid >> 6;
  const int lane = tid & 63;
  const int l15  = lane & 15;
  const int quad = lane >> 4;

  // Q A-fragment: row m = l15, k = quad*8+j
  const u16* qp = (quad < 2) ? qx : qy;
  const int dq = (quad & 1) * 8;
  const short8 qa = *(const short8*)(qp + base + (size_t)(t0 + w * 16 + l15) * DDIM + dq);

  f32x4 Of0 = {0.f, 0.f, 0.f, 0.f};
  f32x4 Of1 = {0.f, 0.f, 0.f, 0.f};
  float l_i[4] = {0.f, 0.f, 0.f, 0.f};

  // K staging params: one 16B chunk per thread per 64-row pass
  const int ks_s = tid >> 2, ks_c = tid & 3;
  const u16* ks_p = (ks_c < 2) ? kx : ky;
  const int ks_d8 = (ks_c & 1) * 8;
  const int ks_col = (ks_c < 2 ? 0 : 16) + ks_d8;

  // V staging params: wave w owns 8 source cols; lane = s-row (2 passes)
  const u16* vs_p = (w < 2) ? vx : vy;
  const int vs_cc = (w & 1) * 8;
  const int vs_cb = (w < 2 ? 0 : 16) + vs_cc;

  #define STAGE(kt, buf)                                                          \
    do {                                                                          \
      const int s0_ = (kt) * 128;                                                 \
      _Pragma("unroll")                                                           \
      for (int p = 0; p < 2; ++p) {                                               \
        const int s = ks_s + p * 64;                                              \
        *(short8*)&Ks[buf][s][ks_col] =                                           \
            *(const short8*)(ks_p + base + (size_t)(s0_ + s) * DDIM + ks_d8);     \
      }                                                                           \
      _Pragma("unroll")                                                           \
      for (int p = 0; p < 2; ++p) {                                               \
        const int sl = lane + p * 64;                                             \
        const short8 v8 =                                                         \
            *(const short8*)(vs_p + base + (size_t)(s0_ + sl) * DDIM + vs_cc);    \
        _Pragma("unroll")                                                         \
        for (int e = 0; e < 8; ++e) Vt[buf][vs_cb + e][sl] = (u16)v8[e];          \
      }                                                                           \
    } while (0)

  STAGE(0, 0);

  for (int kt = 0; kt < TT / 128; ++kt) {
    const int buf = kt & 1;
    __syncthreads();
    if (kt + 1 < TT / 128) STAGE(kt + 1, buf ^ 1);

    // S = Q'.K'^T : 8 MFMAs (col tiles of 16)
    f32x4 Sf[8];
    #pragma unroll
    for (int t = 0; t < 8; ++t) {
      short8 kb = *(const short8*)&Ks[buf][t * 16 + l15][quad * 8];
      f32x4 z = {0.f, 0.f, 0.f, 0.f};
      Sf[t] = __builtin_amdgcn_mfma_f32_16x16x32_bf16(qa, kb, z, 0, 0, 0);
    }

    // p = exp2(S * 0.125*log2e); lane-local denominators; truncate-pack
    #pragma unroll
    for (int reg = 0; reg < 4; ++reg) {
      const int q = w * 16 + quad * 4 + reg;
      float sum = 0.f;
      #pragma unroll
      for (int t = 0; t < 8; ++t) {
        const float p = exp2f(Sf[t][reg] * 0.18033688011112042f);
        sum += p;
        Ps[q][t * 16 + l15] = bft(p);
      }
      l_i[reg] += sum;
    }

    // O += P @ V'   (wave-private Ps rows: no barrier needed)
    #pragma unroll
    for (int sh = 0; sh < 4; ++sh) {
      short8 pa  = *(const short8*)&Ps[w * 16 + l15][sh * 32 + quad * 8];
      short8 vb0 = *(const short8*)&Vt[buf][l15][sh * 32 + quad * 8];
      short8 vb1 = *(const short8*)&Vt[buf][16 + l15][sh * 32 + quad * 8];
      Of0 = __builtin_amdgcn_mfma_f32_16x16x32_bf16(pa, vb0, Of0, 0, 0, 0);
      Of1 = __builtin_amdgcn_mfma_f32_16x16x32_bf16(pa, vb1, Of1, 0, 0, 0);
    }
  }
  #undef STAGE

  // epilogue: reduce denominators (16 lanes/row), normalize, write bf16
  #pragma unroll
  for (int reg = 0; reg < 4; ++reg) {
    float l = l_i[reg];
    #pragma unroll
    for (int off = 8; off >= 1; off >>= 1) l += __shfl_xor(l, off, 16);
    const float inv = 1.0f / l;
    const size_t r = base + (size_t)(t0 + w * 16 + quad * 4 + reg) * DDIM + l15;
    o1[r] = bf(Of0[reg] * inv);
    o2[r] = bf(Of1[reg] * inv);
  }
}

// ---------------------------------------------------------------------------
extern "C" void kernel_launch(void* const* d_in, const int* in_sizes, int n_in,
                              void* d_out, int out_size, void* d_ws, size_t ws_size,
                              hipStream_t stream) {
  const float* x_in  = (const float*)d_in[0];
  const float* y_in  = (const float*)d_in[1];
  const float* Wq    = (const float*)d_in[2];
  const float* Wk    = (const float*)d_in[3];
  const float* Wv    = (const float*)d_in[4];
  const float* Wox   = (const float*)d_in[5];
  const float* box   = (const float*)d_in[6];
  const float* Woy   = (const float*)d_in[7];
  const float* boy   = (const float*)d_in[8];
  const float* ln1xg = (const float*)d_in[9];
  const float* ln1xb = (const float*)d_in[10];
  const float* ln1yg = (const float*)d_in[11];
  const float* ln1yb = (const float*)d_in[12];
  const float* ln2xg = (const float*)d_in[13];
  const float* ln2xb = (const float*)d_in[14];
  const float* ln2yg = (const float*)d_in[15];
  const float* ln2yb = (const float*)d_in[16];
  const float* fxw1  = (const float*)d_in[17];
  const float* fxb1  = (const float*)d_in[18];
  const float* fxw2  = (const float*)d_in[19];
  const float* fxb2  = (const float*)d_in[20];
  const float* fyw1  = (const float*)d_in[21];
  const float* fyb1  = (const float*)d_in[22];
  const float* fyw2  = (const float*)d_in[23];
  const float* fyb2  = (const float*)d_in[24];

  const size_t S = (size_t)BT * DDIM;  // 1,048,576 elems
  float* X = (float*)d_out;
  float* Y = X + S;

  char* wsb = (char*)d_ws;
  auto carve = [&](size_t bytes) { char* p = wsb; wsb += (bytes + 255) & ~(size_t)255; return p; };
  u16* xn  = (u16*)carve(S * 2);
  u16* yn  = (u16*)carve(S * 2);
  u16* qx  = (u16*)carve(S * 2);
  u16* kx  = (u16*)carve(S * 2);
  u16* vx  = (u16*)carve(S * 2);
  u16* qy  = (u16*)carve(S * 2);
  u16* ky  = (u16*)carve(S * 2);
  u16* vy  = (u16*)carve(S * 2);
  u16* ob1 = (u16*)carve(S * 2);
  u16* ob2 = (u16*)carve(S * 2);
  u16* WqT[2], *WkT[2], *WvT[2], *WoxT[2], *WoyT[2];
  u16* f1xT[2], *f1yT[2], *f2xT[2], *f2yT[2];
  for (int l = 0; l < 2; ++l) {
    WqT[l]  = (u16*)carve(16384 * 2);
    WkT[l]  = (u16*)carve(16384 * 2);
    WvT[l]  = (u16*)carve(16384 * 2);
    WoxT[l] = (u16*)carve(16384 * 2);
    WoyT[l] = (u16*)carve(16384 * 2);
    f1xT[l] = (u16*)carve(32768 * 2);
    f1yT[l] = (u16*)carve(32768 * 2);
    f2xT[l] = (u16*)carve(32768 * 2);
    f2yT[l] = (u16*)carve(32768 * 2);
  }

  // weight transpose+convert (all layers, one kernel)
  {
    PrepArgs a;
    int idx = 0;
    for (int l = 0; l < 2; ++l) {
      a.p[idx++] = {Wq  + (size_t)l * 16384, WqT[l],  128, 128};
      a.p[idx++] = {Wk  + (size_t)l * 16384, WkT[l],  128, 128};
      a.p[idx++] = {Wv  + (size_t)l * 16384, WvT[l],  128, 128};
      a.p[idx++] = {Wox + (size_t)l * 16384, WoxT[l], 128, 128};
      a.p[idx++] = {Woy + (size_t)l * 16384, WoyT[l], 128, 128};
      a.p[idx++] = {fxw1 + (size_t)l * 32768, f1xT[l], 128, 256};
      a.p[idx++] = {fyw1 + (size_t)l * 32768, f1yT[l], 128, 256};
      a.p[idx++] = {fxw2 + (size_t)l * 32768, f2xT[l], 256, 128};
      a.p[idx++] = {fyw2 + (size_t)l * 32768, f2yT[l], 256, 128};
    }
    prep_k<<<dim3(4, 4, 18), 256, 0, stream>>>(a);
  }

  // layer-0 LN1 (only standalone LN)
  ln0_k<<<dim3(BT / 4, 2), 256, 0, stream>>>(x_in, y_in, ln1xg, ln1xb, ln1yg, ln1yb, xn, yn);

  for (int l = 0; l < 2; ++l) {
    const size_t bo  = (size_t)l * DDIM;
    const size_t fbo = (size_t)l * FF;

    // QKV (6-way batched): pure bf16 out
    {
      GemmArgs a = {}; a.ln = 0;
      a.p[0] = {yn, WqT[l], nullptr, nullptr, nullptr, qx, nullptr, nullptr};
      a.p[1] = {xn, WkT[l], nullptr, nullptr, nullptr, kx, nullptr, nullptr};
      a.p[2] = {xn, WvT[l], nullptr, nullptr, nullptr, vx, nullptr, nullptr};
      a.p[3] = {xn, WqT[l], nullptr, nullptr, nullptr, qy, nullptr, nullptr};
      a.p[4] = {yn, WkT[l], nullptr, nullptr, nullptr, ky, nullptr, nullptr};
      a.p[5] = {yn, WvT[l], nullptr, nullptr, nullptr, vy, nullptr, nullptr};
      gemmf_k<<<dim3(1, BT / 32, 6), 256, 0, stream>>>(a);
    }
    // fused attention
    attn_k<<<dim3(TT / 64, BB * HH), 256, 0, stream>>>(qx, kx, vx, qy, ky, vy, ob1, ob2);
    // output proj + residual + LN2 -> X (fp32) and xn (bf16)
    {
      const float* resx = (l == 0) ? x_in : X;
      const float* resy = (l == 0) ? y_in : Y;
      GemmArgs a = {}; a.ln = 1;
      a.p[0] = {ob1, WoxT[l], box + bo, resx, X, xn, ln2xg + bo, ln2xb + bo};
      a.p[1] = {ob2, WoyT[l], boy + bo, resy, Y, yn, ln2yg + bo, ln2yb + bo};
      gemmf_k<<<dim3(1, BT / 32, 2), 256, 0, stream>>>(a);
    }
    // fused FFN (FFN1 + gelu + FFN2 + residual); layer 0 fuses next LN1
    {
      FfnArgs a = {}; a.ln = (l == 0) ? 1 : 0;
      if (l == 0) {
        a.p[0] = {xn, f1xT[l], fxb1 + fbo, f2xT[l], fxb2 + bo, X, X, xn,
                  ln1xg + DDIM, ln1xb + DDIM};
        a.p[1] = {yn, f1yT[l], fyb1 + fbo, f2yT[l], fyb2 + bo, Y, Y, yn,
                  ln1yg + DDIM, ln1yb + DDIM};
      } else {
        a.p[0] = {xn, f1xT[l], fxb1 + fbo, f2xT[l], fxb2 + bo, X, X, nullptr,
                  nullptr, nullptr};
        a.p[1] = {yn, f1yT[l], fyb1 + fbo, f2yT[l], fyb2 + bo, Y, Y, nullptr,
                  nullptr, nullptr};
      }
      ffn_k<<<dim3(BT / 32, 2), 256, 0, stream>>>(a);
    }
  }
}

// Round 11
// 251.526 us; speedup vs baseline: 4.4090x; 1.0770x over previous
//
#include <hip/hip_runtime.h>
#include <cstddef>

#define BB   8
#define TT   1024
#define DDIM 128
#define HH   8
#define DHH  16
#define FF   256
#define BT   (BB * TT)   // 8192

typedef unsigned short u16;
typedef __attribute__((ext_vector_type(8))) short short8;
typedef __attribute__((ext_vector_type(4))) float f32x4;

__device__ __forceinline__ u16 bf(float x) {
  unsigned u = __builtin_bit_cast(unsigned, x);
  u += 0x7fffu + ((u >> 16) & 1u);   // RTN-even
  return (u16)(u >> 16);
}
__device__ __forceinline__ u16 bft(float x) {           // truncate (P in [0,1])
  return (u16)(__builtin_bit_cast(unsigned, x) >> 16);
}
__device__ __forceinline__ float gelu_f(float x) {
  const float t = x * (0.79788456f + 0.03567740814f * x * x);
  return x / (1.0f + __expf(-2.0f * t));
}

// ---------------------------------------------------------------------------
// Weight prep: fp32 (K,N) -> bf16 (N,K)  (transpose + convert), 18 matrices.
// ---------------------------------------------------------------------------
struct PrepP { const float* W; u16* Wt; int K; int N; };
struct PrepArgs { PrepP p[18]; };

__global__ __launch_bounds__(256) void prep_k(PrepArgs a) {
  const PrepP pp = a.p[blockIdx.z];
  const int n0 = blockIdx.x * 64, k0 = blockIdx.y * 64;
  if (n0 >= pp.N || k0 >= pp.K) return;
  __shared__ float tile[64][65];
  const int tid = threadIdx.x;
  #pragma unroll
  for (int t = tid; t < 1024; t += 256) {
    const int kk = t >> 4, nn4 = (t & 15) << 2;
    float4 v = *(const float4*)(pp.W + (size_t)(k0 + kk) * pp.N + n0 + nn4);
    tile[nn4 + 0][kk] = v.x; tile[nn4 + 1][kk] = v.y;
    tile[nn4 + 2][kk] = v.z; tile[nn4 + 3][kk] = v.w;
  }
  __syncthreads();
  #pragma unroll
  for (int t = tid; t < 1024; t += 256) {
    const int nn = t >> 4, kk4 = (t & 15) << 2;
    ushort4 o;
    o.x = bf(tile[nn][kk4 + 0]); o.y = bf(tile[nn][kk4 + 1]);
    o.z = bf(tile[nn][kk4 + 2]); o.w = bf(tile[nn][kk4 + 3]);
    *(ushort4*)(pp.Wt + (size_t)(n0 + nn) * pp.K + k0 + kk4) = o;
  }
}

// ---------------------------------------------------------------------------
// Standalone LN (layer-0 LN1 only): fp32 in -> bf16 out. 4 rows / 256-thr block.
// ---------------------------------------------------------------------------
__global__ __launch_bounds__(256) void ln0_k(const float* __restrict__ X,
                                             const float* __restrict__ Y,
                                             const float* __restrict__ gx,
                                             const float* __restrict__ bx,
                                             const float* __restrict__ gy,
                                             const float* __restrict__ by,
                                             u16* __restrict__ ox,
                                             u16* __restrict__ oy) {
  const int which = blockIdx.y;
  const float* in = which ? Y : X;
  const float* g  = which ? gy : gx;
  const float* b  = which ? by : bx;
  u16* out        = which ? oy : ox;
  const int row  = blockIdx.x * 4 + (threadIdx.x >> 6);
  const int lane = threadIdx.x & 63;

  float2 v = *(const float2*)(in + (size_t)row * DDIM + lane * 2);
  float s  = v.x + v.y;
  float sq = v.x * v.x + v.y * v.y;
  #pragma unroll
  for (int off = 32; off >= 1; off >>= 1) {
    s  += __shfl_xor(s, off);
    sq += __shfl_xor(sq, off);
  }
  const float mean = s * (1.0f / DDIM);
  const float var  = sq * (1.0f / DDIM) - mean * mean;
  const float r    = rsqrtf(var + 1e-5f);
  float2 gg = *(const float2*)(g + lane * 2);
  float2 bb = *(const float2*)(b + lane * 2);
  ushort2 o;
  o.x = bf((v.x - mean) * r * gg.x + bb.x);
  o.y = bf((v.y - mean) * r * gg.y + bb.y);
  *(ushort2*)(out + (size_t)row * DDIM + lane * 2) = o;
}

// ---------------------------------------------------------------------------
// bf16 MFMA GEMM, 32x128 tile, 256 threads = 4 waves. BK=128 single-barrier.
// Fused epilogue: bias / +res fp32 / bf16 out / per-row LN / TRANSPOSED V out
// (outT: vT[(b*8+h)*16+c][s] — regs are 4 consecutive tokens => 8B stores).
// ---------------------------------------------------------------------------
struct GemmP { const u16* A; const u16* Wt; const float* bias; const float* res;
               float* outF; u16* outB; const float* g; const float* b; u16* outT; };
struct GemmArgs { GemmP p[6]; int ln; };

__global__ __launch_bounds__(256) void gemmf_k(GemmArgs a) {
  const GemmP pp = a.p[blockIdx.z];
  const int m0 = blockIdx.y * 32;
  __shared__ __align__(16) u16 As[32][136];
  __shared__ __align__(16) u16 Bs[128][136];
  __shared__ float2 stats[32][2];
  const int tid  = threadIdx.x;
  const int w    = tid >> 6;
  const int lane = tid & 63;
  const int l15  = lane & 15;
  const int quad = lane >> 4;
  const int wr = w & 1, wc = w >> 1;

  f32x4 acc[4];
  #pragma unroll
  for (int j = 0; j < 4; ++j) acc[j] = {0.f, 0.f, 0.f, 0.f};

  #pragma unroll
  for (int t = tid; t < 512; t += 256) {
    const int r = t >> 4, g8 = (t & 15) << 3;
    *(short8*)&As[r][g8] = *(const short8*)(pp.A + (size_t)(m0 + r) * 128 + g8);
  }
  #pragma unroll
  for (int t = tid; t < 2048; t += 256) {
    const int r = t >> 4, g8 = (t & 15) << 3;
    *(short8*)&Bs[r][g8] = *(const short8*)(pp.Wt + (size_t)r * 128 + g8);
  }
  __syncthreads();
  #pragma unroll
  for (int ks = 0; ks < 4; ++ks) {
    const short8 ar = *(const short8*)&As[wr * 16 + l15][ks * 32 + quad * 8];
    #pragma unroll
    for (int j = 0; j < 4; ++j) {
      const short8 br = *(const short8*)&Bs[wc * 64 + j * 16 + l15][ks * 32 + quad * 8];
      acc[j] = __builtin_amdgcn_mfma_f32_16x16x32_bf16(ar, br, acc[j], 0, 0, 0);
    }
  }

  // ---- transposed V output path (no bias/res/ln) ----
  if (pp.outT) {
    const int m_base = m0 + wr * 16 + quad * 4;
    const int bb_ = m_base >> 10, s = m_base & 1023;
    #pragma unroll
    for (int j = 0; j < 4; ++j) {
      const int n = wc * 64 + j * 16 + l15;
      const int h = n >> 4, c = n & 15;
      ushort4 o;
      o.x = bf(acc[j][0]); o.y = bf(acc[j][1]);
      o.z = bf(acc[j][2]); o.w = bf(acc[j][3]);
      *(ushort4*)(pp.outT + (((size_t)(bb_ * 8 + h) * 16 + c) << 10) + s) = o;
    }
    return;
  }

  // ---- epilogue: bias / res, raw fp32 store ----
  #pragma unroll
  for (int j = 0; j < 4; ++j) {
    const int n = wc * 64 + j * 16 + l15;
    const float bias_v = pp.bias ? pp.bias[n] : 0.f;
    #pragma unroll
    for (int reg = 0; reg < 4; ++reg) {
      const int m = m0 + wr * 16 + quad * 4 + reg;
      float v = acc[j][reg] + bias_v;
      if (pp.res) v += pp.res[(size_t)m * 128 + n];
      acc[j][reg] = v;
      if (pp.outF) pp.outF[(size_t)m * 128 + n] = v;
    }
  }

  if (!a.ln) {
    if (pp.outB) {
      #pragma unroll
      for (int j = 0; j < 4; ++j) {
        const int n = wc * 64 + j * 16 + l15;
        #pragma unroll
        for (int reg = 0; reg < 4; ++reg) {
          const int m = m0 + wr * 16 + quad * 4 + reg;
          pp.outB[(size_t)m * 128 + n] = bf(acc[j][reg]);
        }
      }
    }
    return;
  }

  // ---- fused LayerNorm ----
  #pragma unroll
  for (int reg = 0; reg < 4; ++reg) {
    float s = 0.f, q = 0.f;
    #pragma unroll
    for (int j = 0; j < 4; ++j) { const float v = acc[j][reg]; s += v; q += v * v; }
    #pragma unroll
    for (int off = 8; off >= 1; off >>= 1) {
      s += __shfl_xor(s, off, 16);
      q += __shfl_xor(q, off, 16);
    }
    if (l15 == 0) stats[wr * 16 + quad * 4 + reg][wc] = make_float2(s, q);
  }
  __syncthreads();
  #pragma unroll
  for (int reg = 0; reg < 4; ++reg) {
    const int mloc = wr * 16 + quad * 4 + reg;
    const float2 s0 = stats[mloc][0], s1 = stats[mloc][1];
    const float mean = (s0.x + s1.x) * (1.0f / 128.f);
    const float var  = (s0.y + s1.y) * (1.0f / 128.f) - mean * mean;
    const float r    = rsqrtf(var + 1e-5f);
    #pragma unroll
    for (int j = 0; j < 4; ++j) {
      const int n = wc * 64 + j * 16 + l15;
      pp.outB[(size_t)(m0 + mloc) * 128 + n] =
          bf((acc[j][reg] - mean) * r * pp.g[n] + pp.b[n]);
    }
  }
}

// ---------------------------------------------------------------------------
// Fused FFN: out = gelu(A@W1+b1)@W2 + b2 [+res] per 32-row tile, h in LDS.
// ---------------------------------------------------------------------------
struct FfnP { const u16* A; const u16* W1t; const float* b1;
              const u16* W2t; const float* b2; const float* res;
              float* outF; u16* outB; const float* g; const float* b; };
struct FfnArgs { FfnP p[2]; int ln; };

__global__ __launch_bounds__(256) void ffn_k(FfnArgs a) {
  const FfnP pp = a.p[blockIdx.y];
  const int m0 = blockIdx.x * 32;
  __shared__ __align__(16) u16 As[32][136];
  __shared__ __align__(16) u16 Bs[128][136];
  __shared__ __align__(16) u16 Hs[32][264];
  __shared__ float2 stats[32][2];
  const int tid  = threadIdx.x;
  const int w    = tid >> 6;
  const int lane = tid & 63;
  const int l15  = lane & 15;
  const int quad = lane >> 4;
  const int wr = w & 1, wc = w >> 1;

  #pragma unroll
  for (int t = tid; t < 512; t += 256) {
    const int r = t >> 4, g8 = (t & 15) << 3;
    *(short8*)&As[r][g8] = *(const short8*)(pp.A + (size_t)(m0 + r) * 128 + g8);
  }

  // ---- FFN1: h = gelu(A@W1+b1) in LDS, two 128-col halves ----
  for (int nh = 0; nh < 2; ++nh) {
    #pragma unroll
    for (int t = tid; t < 2048; t += 256) {
      const int r = t >> 4, g8 = (t & 15) << 3;
      *(short8*)&Bs[r][g8] = *(const short8*)(pp.W1t + (size_t)(nh * 128 + r) * 128 + g8);
    }
    __syncthreads();
    f32x4 acc[4];
    #pragma unroll
    for (int j = 0; j < 4; ++j) acc[j] = {0.f, 0.f, 0.f, 0.f};
    #pragma unroll
    for (int ks = 0; ks < 4; ++ks) {
      const short8 ar = *(const short8*)&As[wr * 16 + l15][ks * 32 + quad * 8];
      #pragma unroll
      for (int j = 0; j < 4; ++j) {
        const short8 br = *(const short8*)&Bs[wc * 64 + j * 16 + l15][ks * 32 + quad * 8];
        acc[j] = __builtin_amdgcn_mfma_f32_16x16x32_bf16(ar, br, acc[j], 0, 0, 0);
      }
    }
    #pragma unroll
    for (int j = 0; j < 4; ++j) {
      const int n = wc * 64 + j * 16 + l15;
      const float bias_v = pp.b1[nh * 128 + n];
      #pragma unroll
      for (int reg = 0; reg < 4; ++reg) {
        const int mloc = wr * 16 + quad * 4 + reg;
        Hs[mloc][nh * 128 + n] = bf(gelu_f(acc[j][reg] + bias_v));
      }
    }
    __syncthreads();
  }

  // ---- FFN2: out = h@W2 + b2 (+res), two K-halves ----
  f32x4 acc2[4];
  #pragma unroll
  for (int j = 0; j < 4; ++j) acc2[j] = {0.f, 0.f, 0.f, 0.f};
  for (int kh = 0; kh < 2; ++kh) {
    #pragma unroll
    for (int t = tid; t < 2048; t += 256) {
      const int r = t >> 4, g8 = (t & 15) << 3;
      *(short8*)&Bs[r][g8] = *(const short8*)(pp.W2t + (size_t)r * 256 + kh * 128 + g8);
    }
    __syncthreads();
    #pragma unroll
    for (int ks = 0; ks < 4; ++ks) {
      const short8 ar = *(const short8*)&Hs[wr * 16 + l15][kh * 128 + ks * 32 + quad * 8];
      #pragma unroll
      for (int j = 0; j < 4; ++j) {
        const short8 br = *(const short8*)&Bs[wc * 64 + j * 16 + l15][ks * 32 + quad * 8];
        acc2[j] = __builtin_amdgcn_mfma_f32_16x16x32_bf16(ar, br, acc2[j], 0, 0, 0);
      }
    }
    __syncthreads();
  }

  // ---- epilogue ----
  #pragma unroll
  for (int j = 0; j < 4; ++j) {
    const int n = wc * 64 + j * 16 + l15;
    const float bias_v = pp.b2[n];
    #pragma unroll
    for (int reg = 0; reg < 4; ++reg) {
      const int m = m0 + wr * 16 + quad * 4 + reg;
      float v = acc2[j][reg] + bias_v + pp.res[(size_t)m * 128 + n];
      acc2[j][reg] = v;
      pp.outF[(size_t)m * 128 + n] = v;
    }
  }
  if (!a.ln) return;
  #pragma unroll
  for (int reg = 0; reg < 4; ++reg) {
    float s = 0.f, q = 0.f;
    #pragma unroll
    for (int j = 0; j < 4; ++j) { const float v = acc2[j][reg]; s += v; q += v * v; }
    #pragma unroll
    for (int off = 8; off >= 1; off >>= 1) {
      s += __shfl_xor(s, off, 16);
      q += __shfl_xor(q, off, 16);
    }
    if (l15 == 0) stats[wr * 16 + quad * 4 + reg][wc] = make_float2(s, q);
  }
  __syncthreads();
  #pragma unroll
  for (int reg = 0; reg < 4; ++reg) {
    const int mloc = wr * 16 + quad * 4 + reg;
    const float2 s0 = stats[mloc][0], s1 = stats[mloc][1];
    const float mean = (s0.x + s1.x) * (1.0f / 128.f);
    const float var  = (s0.y + s1.y) * (1.0f / 128.f) - mean * mean;
    const float r    = rsqrtf(var + 1e-5f);
    #pragma unroll
    for (int j = 0; j < 4; ++j) {
      const int n = wc * 64 + j * 16 + l15;
      pp.outB[(size_t)(m0 + mloc) * 128 + n] =
          bf((acc2[j][reg] - mean) * r * pp.g[n] + pp.b[n]);
    }
  }
}

// ---------------------------------------------------------------------------
// MFMA flash attention. S^T orientation: Sf = mfma(kb, qa) => lane's 4 regs
// are 4 consecutive KEYS at one query => P packs as ds_write_b64; denominator
// is a lane-local scalar (2 shuffles at end). V comes pre-transposed from the
// QKV GEMM (vT[bh*16+c][s]) => staging is pure b128 copy. 64-key dbuf tiles.
// ---------------------------------------------------------------------------
__global__ __launch_bounds__(256) void attn_k(const u16* __restrict__ qx,
                                              const u16* __restrict__ kx,
                                              const u16* __restrict__ qy,
                                              const u16* __restrict__ ky,
                                              const u16* __restrict__ vtx,
                                              const u16* __restrict__ vty,
                                              u16* __restrict__ o1,
                                              u16* __restrict__ o2) {
  const int t0 = blockIdx.x * 64;
  const int bh = blockIdx.y;
  const int b = bh >> 3, h = bh & 7;
  const size_t base = (size_t)b * TT * DDIM + h * DHH;

  __shared__ __align__(16) u16 Ks[2][64][40];  // [buf][s][d0..31]
  __shared__ __align__(16) u16 Vt[2][32][72];  // [buf][c][s0..63]
  __shared__ __align__(16) u16 Ps[64][72];     // [q][s0..63] (wave-private rows)

  const int tid  = threadIdx.x;
  const int w    = tid >> 6;
  const int lane = tid & 63;
  const int l15  = lane & 15;
  const int quad = lane >> 4;

  // Q fragment (B-operand now; same layout): row l15, k = quad*8+j
  const u16* qp = (quad < 2) ? qx : qy;
  const int dq = (quad & 1) * 8;
  const short8 qa = *(const short8*)(qp + base + (size_t)(t0 + w * 16 + l15) * DDIM + dq);

  f32x4 Of0 = {0.f, 0.f, 0.f, 0.f};
  f32x4 Of1 = {0.f, 0.f, 0.f, 0.f};
  float l_i = 0.f;

  // K staging: one b128 per thread
  const int ks_s = tid >> 2, ks_c = tid & 3;
  const u16* ks_p = (ks_c < 2) ? kx : ky;
  const int ks_d8 = (ks_c & 1) * 8;
  const int ks_col = (ks_c < 2 ? 0 : 16) + ks_d8;

  // V staging: pure b128 copy from pre-transposed vT
  const int vs_c = tid >> 3;              // 0..31
  const int vs_s8 = (tid & 7) * 8;        // 0..56
  const u16* vs_row = (vs_c < 16) ? (vtx + (((size_t)bh * 16 + vs_c) << 10))
                                  : (vty + (((size_t)bh * 16 + (vs_c - 16)) << 10));

  #define STAGE(kt, buf)                                                          \
    do {                                                                          \
      const int s0_ = (kt) * 64;                                                  \
      *(short8*)&Ks[buf][ks_s][ks_col] =                                          \
          *(const short8*)(ks_p + base + (size_t)(s0_ + ks_s) * DDIM + ks_d8);    \
      *(short8*)&Vt[buf][vs_c][vs_s8] = *(const short8*)(vs_row + s0_ + vs_s8);   \
    } while (0)

  STAGE(0, 0);

  for (int kt = 0; kt < TT / 64; ++kt) {
    const int buf = kt & 1;
    __syncthreads();
    if (kt + 1 < TT / 64) STAGE(kt + 1, buf ^ 1);

    // S^T = K'.Q'^T : 4 MFMAs (operands swapped => transposed result)
    f32x4 Sf[4];
    #pragma unroll
    for (int t = 0; t < 4; ++t) {
      short8 kb = *(const short8*)&Ks[buf][t * 16 + l15][quad * 8];
      f32x4 z = {0.f, 0.f, 0.f, 0.f};
      Sf[t] = __builtin_amdgcn_mfma_f32_16x16x32_bf16(kb, qa, z, 0, 0, 0);
    }

    // exp; regs = 4 consecutive keys at query l15 -> packed b64 P-writes
    #pragma unroll
    for (int t = 0; t < 4; ++t) {
      const float p0 = exp2f(Sf[t][0] * 0.18033688011112042f);
      const float p1 = exp2f(Sf[t][1] * 0.18033688011112042f);
      const float p2 = exp2f(Sf[t][2] * 0.18033688011112042f);
      const float p3 = exp2f(Sf[t][3] * 0.18033688011112042f);
      l_i += p0 + p1 + p2 + p3;
      ushort4 pk;
      pk.x = bft(p0); pk.y = bft(p1); pk.z = bft(p2); pk.w = bft(p3);
      *(ushort4*)&Ps[w * 16 + l15][t * 16 + quad * 4] = pk;
    }

    // O += P @ V'  (wave-private Ps rows: no barrier)
    #pragma unroll
    for (int sh = 0; sh < 2; ++sh) {
      short8 pa  = *(const short8*)&Ps[w * 16 + l15][sh * 32 + quad * 8];
      short8 vb0 = *(const short8*)&Vt[buf][l15][sh * 32 + quad * 8];
      short8 vb1 = *(const short8*)&Vt[buf][16 + l15][sh * 32 + quad * 8];
      Of0 = __builtin_amdgcn_mfma_f32_16x16x32_bf16(pa, vb0, Of0, 0, 0, 0);
      Of1 = __builtin_amdgcn_mfma_f32_16x16x32_bf16(pa, vb1, Of1, 0, 0, 0);
    }
  }
  #undef STAGE

  // denom: sum across the 4 quads holding query l15's keys, then distribute
  l_i += __shfl_xor(l_i, 16);
  l_i += __shfl_xor(l_i, 32);
  #pragma unroll
  for (int reg = 0; reg < 4; ++reg) {
    const float lq = __shfl(l_i, quad * 4 + reg, 16);  // denom of query quad*4+reg
    const float inv = 1.0f / lq;
    const size_t r = base + (size_t)(t0 + w * 16 + quad * 4 + reg) * DDIM + l15;
    o1[r] = bf(Of0[reg] * inv);
    o2[r] = bf(Of1[reg] * inv);
  }
}

// ---------------------------------------------------------------------------
extern "C" void kernel_launch(void* const* d_in, const int* in_sizes, int n_in,
                              void* d_out, int out_size, void* d_ws, size_t ws_size,
                              hipStream_t stream) {
  const float* x_in  = (const float*)d_in[0];
  const float* y_in  = (const float*)d_in[1];
  const float* Wq    = (const float*)d_in[2];
  const float* Wk    = (const float*)d_in[3];
  const float* Wv    = (const float*)d_in[4];
  const float* Wox   = (const float*)d_in[5];
  const float* box   = (const float*)d_in[6];
  const float* Woy   = (const float*)d_in[7];
  const float* boy   = (const float*)d_in[8];
  const float* ln1xg = (const float*)d_in[9];
  const float* ln1xb = (const float*)d_in[10];
  const float* ln1yg = (const float*)d_in[11];
  const float* ln1yb = (const float*)d_in[12];
  const float* ln2xg = (const float*)d_in[13];
  const float* ln2xb = (const float*)d_in[14];
  const float* ln2yg = (const float*)d_in[15];
  const float* ln2yb = (const float*)d_in[16];
  const float* fxw1  = (const float*)d_in[17];
  const float* fxb1  = (const float*)d_in[18];
  const float* fxw2  = (const float*)d_in[19];
  const float* fxb2  = (const float*)d_in[20];
  const float* fyw1  = (const float*)d_in[21];
  const float* fyb1  = (const float*)d_in[22];
  const float* fyw2  = (const float*)d_in[23];
  const float* fyb2  = (const float*)d_in[24];

  const size_t S = (size_t)BT * DDIM;  // 1,048,576 elems
  float* X = (float*)d_out;
  float* Y = X + S;

  char* wsb = (char*)d_ws;
  auto carve = [&](size_t bytes) { char* p = wsb; wsb += (bytes + 255) & ~(size_t)255; return p; };
  u16* xn  = (u16*)carve(S * 2);
  u16* yn  = (u16*)carve(S * 2);
  u16* qx  = (u16*)carve(S * 2);
  u16* kx  = (u16*)carve(S * 2);
  u16* qy  = (u16*)carve(S * 2);
  u16* ky  = (u16*)carve(S * 2);
  u16* vxT = (u16*)carve(S * 2);   // vT[(b*8+h)*16+c][s]
  u16* vyT = (u16*)carve(S * 2);
  u16* ob1 = (u16*)carve(S * 2);
  u16* ob2 = (u16*)carve(S * 2);
  u16* WqT[2], *WkT[2], *WvT[2], *WoxT[2], *WoyT[2];
  u16* f1xT[2], *f1yT[2], *f2xT[2], *f2yT[2];
  for (int l = 0; l < 2; ++l) {
    WqT[l]  = (u16*)carve(16384 * 2);
    WkT[l]  = (u16*)carve(16384 * 2);
    WvT[l]  = (u16*)carve(16384 * 2);
    WoxT[l] = (u16*)carve(16384 * 2);
    WoyT[l] = (u16*)carve(16384 * 2);
    f1xT[l] = (u16*)carve(32768 * 2);
    f1yT[l] = (u16*)carve(32768 * 2);
    f2xT[l] = (u16*)carve(32768 * 2);
    f2yT[l] = (u16*)carve(32768 * 2);
  }

  // weight transpose+convert (all layers, one kernel)
  {
    PrepArgs a;
    int idx = 0;
    for (int l = 0; l < 2; ++l) {
      a.p[idx++] = {Wq  + (size_t)l * 16384, WqT[l],  128, 128};
      a.p[idx++] = {Wk  + (size_t)l * 16384, WkT[l],  128, 128};
      a.p[idx++] = {Wv  + (size_t)l * 16384, WvT[l],  128, 128};
      a.p[idx++] = {Wox + (size_t)l * 16384, WoxT[l], 128, 128};
      a.p[idx++] = {Woy + (size_t)l * 16384, WoyT[l], 128, 128};
      a.p[idx++] = {fxw1 + (size_t)l * 32768, f1xT[l], 128, 256};
      a.p[idx++] = {fyw1 + (size_t)l * 32768, f1yT[l], 128, 256};
      a.p[idx++] = {fxw2 + (size_t)l * 32768, f2xT[l], 256, 128};
      a.p[idx++] = {fyw2 + (size_t)l * 32768, f2yT[l], 256, 128};
    }
    prep_k<<<dim3(4, 4, 18), 256, 0, stream>>>(a);
  }

  // layer-0 LN1 (only standalone LN)
  ln0_k<<<dim3(BT / 4, 2), 256, 0, stream>>>(x_in, y_in, ln1xg, ln1xb, ln1yg, ln1yb, xn, yn);

  for (int l = 0; l < 2; ++l) {
    const size_t bo  = (size_t)l * DDIM;
    const size_t fbo = (size_t)l * FF;

    // QKV (6-way batched); V ops write transposed
    {
      GemmArgs a = {}; a.ln = 0;
      a.p[0] = {yn, WqT[l], nullptr, nullptr, nullptr, qx, nullptr, nullptr, nullptr};
      a.p[1] = {xn, WkT[l], nullptr, nullptr, nullptr, kx, nullptr, nullptr, nullptr};
      a.p[2] = {xn, WvT[l], nullptr, nullptr, nullptr, nullptr, nullptr, nullptr, vxT};
      a.p[3] = {xn, WqT[l], nullptr, nullptr, nullptr, qy, nullptr, nullptr, nullptr};
      a.p[4] = {yn, WkT[l], nullptr, nullptr, nullptr, ky, nullptr, nullptr, nullptr};
      a.p[5] = {yn, WvT[l], nullptr, nullptr, nullptr, nullptr, nullptr, nullptr, vyT};
      gemmf_k<<<dim3(1, BT / 32, 6), 256, 0, stream>>>(a);
    }
    // fused attention
    attn_k<<<dim3(TT / 64, BB * HH), 256, 0, stream>>>(qx, kx, qy, ky, vxT, vyT, ob1, ob2);
    // output proj + residual + LN2 -> X (fp32) and xn (bf16)
    {
      const float* resx = (l == 0) ? x_in : X;
      const float* resy = (l == 0) ? y_in : Y;
      GemmArgs a = {}; a.ln = 1;
      a.p[0] = {ob1, WoxT[l], box + bo, resx, X, xn, ln2xg + bo, ln2xb + bo, nullptr};
      a.p[1] = {ob2, WoyT[l], boy + bo, resy, Y, yn, ln2yg + bo, ln2yb + bo, nullptr};
      gemmf_k<<<dim3(1, BT / 32, 2), 256, 0, stream>>>(a);
    }
    // fused FFN (FFN1 + gelu + FFN2 + residual); layer 0 fuses next LN1
    {
      FfnArgs a = {}; a.ln = (l == 0) ? 1 : 0;
      if (l == 0) {
        a.p[0] = {xn, f1xT[l], fxb1 + fbo, f2xT[l], fxb2 + bo, X, X, xn,
                  ln1xg + DDIM, ln1xb + DDIM};
        a.p[1] = {yn, f1yT[l], fyb1 + fbo, f2yT[l], fyb2 + bo, Y, Y, yn,
                  ln1yg + DDIM, ln1yb + DDIM};
      } else {
        a.p[0] = {xn, f1xT[l], fxb1 + fbo, f2xT[l], fxb2 + bo, X, X, nullptr,
                  nullptr, nullptr};
        a.p[1] = {yn, f1yT[l], fyb1 + fbo, f2yT[l], fyb2 + bo, Y, Y, nullptr,
                  nullptr, nullptr};
      }
      ffn_k<<<dim3(BT / 32, 2), 256, 0, stream>>>(a);
    }
  }
}

// Round 12
// 226.380 us; speedup vs baseline: 4.8987x; 1.1111x over previous
//
#include <hip/hip_runtime.h>
#include <cstddef>

#define BB   8
#define TT   1024
#define DDIM 128
#define HH   8
#define DHH  16
#define FF   256
#define BT   (BB * TT)   // 8192

typedef unsigned short u16;
typedef __attribute__((ext_vector_type(8))) short short8;
typedef __attribute__((ext_vector_type(4))) float f32x4;

__device__ __forceinline__ u16 bf(float x) {
  unsigned u = __builtin_bit_cast(unsigned, x);
  u += 0x7fffu + ((u >> 16) & 1u);   // RTN-even
  return (u16)(u >> 16);
}
__device__ __forceinline__ u16 bft(float x) {           // truncate (P in [0,1])
  return (u16)(__builtin_bit_cast(unsigned, x) >> 16);
}
__device__ __forceinline__ float gelu_f(float x) {
  const float t = x * (0.79788456f + 0.03567740814f * x * x);
  return x / (1.0f + __expf(-2.0f * t));
}

// ---------------------------------------------------------------------------
// setup_k: units 0..103 = weight transpose tiles (fp32 (K,N) -> bf16 (N,K));
// units 104..4199 = layer-0 LN1 (4 rows per unit). Decomposition verified in R9.
// ---------------------------------------------------------------------------
struct PrepP { const float* W; u16* Wt; };
struct SetupArgs {
  PrepP prep[18];   // [0..9] K128N128, [10..13] K128N256 (f1), [14..17] K256N128 (f2)
  const float* x_in; const float* y_in;
  const float* ln1xg; const float* ln1xb; const float* ln1yg; const float* ln1yb;
  u16* xn; u16* yn;
};

__global__ __launch_bounds__(256) void setup_k(SetupArgs a) {
  __shared__ float tile[64][65];
  const int u = blockIdx.x;
  const int tid = threadIdx.x;
  if (u < 104) {
    int idx, ti, K, N;
    if (u < 40)      { idx = u >> 2;               ti = u & 3;        K = 128; N = 128; }
    else if (u < 72) { idx = 10 + ((u - 40) >> 3); ti = (u - 40) & 7; K = 128; N = 256; }
    else             { idx = 14 + ((u - 72) >> 3); ti = (u - 72) & 7; K = 256; N = 128; }
    const int n0 = (N == 256) ? (ti & 3) * 64 : (ti & 1) * 64;
    const int k0 = (N == 256) ? (ti >> 2) * 64 : (ti >> 1) * 64;
    const PrepP pp = a.prep[idx];
    #pragma unroll
    for (int t = tid; t < 1024; t += 256) {
      const int kk = t >> 4, nn4 = (t & 15) << 2;
      float4 v = *(const float4*)(pp.W + (size_t)(k0 + kk) * N + n0 + nn4);
      tile[nn4 + 0][kk] = v.x; tile[nn4 + 1][kk] = v.y;
      tile[nn4 + 2][kk] = v.z; tile[nn4 + 3][kk] = v.w;
    }
    __syncthreads();
    #pragma unroll
    for (int t = tid; t < 1024; t += 256) {
      const int nn = t >> 4, kk4 = (t & 15) << 2;
      ushort4 o;
      o.x = bf(tile[nn][kk4 + 0]); o.y = bf(tile[nn][kk4 + 1]);
      o.z = bf(tile[nn][kk4 + 2]); o.w = bf(tile[nn][kk4 + 3]);
      *(ushort4*)(pp.Wt + (size_t)(n0 + nn) * K + k0 + kk4) = o;
    }
  } else {
    const int v_ = u - 104;
    const int which = v_ & 1;
    const int row   = (v_ >> 1) * 4 + (tid >> 6);
    const int lane  = tid & 63;
    const float* in = which ? a.y_in : a.x_in;
    const float* g  = which ? a.ln1yg : a.ln1xg;
    const float* b  = which ? a.ln1yb : a.ln1xb;
    u16* out        = which ? a.yn : a.xn;

    float2 v = *(const float2*)(in + (size_t)row * DDIM + lane * 2);
    float s  = v.x + v.y;
    float sq = v.x * v.x + v.y * v.y;
    #pragma unroll
    for (int off = 32; off >= 1; off >>= 1) {
      s  += __shfl_xor(s, off);
      sq += __shfl_xor(sq, off);
    }
    const float mean = s * (1.0f / DDIM);
    const float var  = sq * (1.0f / DDIM) - mean * mean;
    const float r    = rsqrtf(var + 1e-5f);
    float2 gg = *(const float2*)(g + lane * 2);
    float2 bb = *(const float2*)(b + lane * 2);
    ushort2 o;
    o.x = bf((v.x - mean) * r * gg.x + bb.x);
    o.y = bf((v.y - mean) * r * gg.y + bb.y);
    *(ushort2*)(out + (size_t)row * DDIM + lane * 2) = o;
  }
}

// ---------------------------------------------------------------------------
// bf16 MFMA GEMM (QKV), 32x128 tile, 4 waves, BK=128 single-barrier.
// Epilogue: bf16 out (Q/K) or TRANSPOSED V out (vT[(b*8+h)*16+c][s]).
// ---------------------------------------------------------------------------
struct GemmP { const u16* A; const u16* Wt; u16* outB; u16* outT; };
struct GemmArgs { GemmP p[6]; };

__global__ __launch_bounds__(256) void gemmf_k(GemmArgs a) {
  const GemmP pp = a.p[blockIdx.z];
  const int m0 = blockIdx.y * 32;
  __shared__ __align__(16) u16 As[32][136];
  __shared__ __align__(16) u16 Bs[128][136];
  const int tid  = threadIdx.x;
  const int w    = tid >> 6;
  const int lane = tid & 63;
  const int l15  = lane & 15;
  const int quad = lane >> 4;
  const int wr = w & 1, wc = w >> 1;

  f32x4 acc[4];
  #pragma unroll
  for (int j = 0; j < 4; ++j) acc[j] = {0.f, 0.f, 0.f, 0.f};

  #pragma unroll
  for (int t = tid; t < 512; t += 256) {
    const int r = t >> 4, g8 = (t & 15) << 3;
    *(short8*)&As[r][g8] = *(const short8*)(pp.A + (size_t)(m0 + r) * 128 + g8);
  }
  #pragma unroll
  for (int t = tid; t < 2048; t += 256) {
    const int r = t >> 4, g8 = (t & 15) << 3;
    *(short8*)&Bs[r][g8] = *(const short8*)(pp.Wt + (size_t)r * 128 + g8);
  }
  __syncthreads();
  #pragma unroll
  for (int ks = 0; ks < 4; ++ks) {
    const short8 ar = *(const short8*)&As[wr * 16 + l15][ks * 32 + quad * 8];
    #pragma unroll
    for (int j = 0; j < 4; ++j) {
      const short8 br = *(const short8*)&Bs[wc * 64 + j * 16 + l15][ks * 32 + quad * 8];
      acc[j] = __builtin_amdgcn_mfma_f32_16x16x32_bf16(ar, br, acc[j], 0, 0, 0);
    }
  }

  if (pp.outT) {
    const int m_base = m0 + wr * 16 + quad * 4;
    const int bb_ = m_base >> 10, s = m_base & 1023;
    #pragma unroll
    for (int j = 0; j < 4; ++j) {
      const int n = wc * 64 + j * 16 + l15;
      const int h = n >> 4, c = n & 15;
      ushort4 o;
      o.x = bf(acc[j][0]); o.y = bf(acc[j][1]);
      o.z = bf(acc[j][2]); o.w = bf(acc[j][3]);
      *(ushort4*)(pp.outT + (((size_t)(bb_ * 8 + h) * 16 + c) << 10) + s) = o;
    }
    return;
  }

  #pragma unroll
  for (int j = 0; j < 4; ++j) {
    const int n = wc * 64 + j * 16 + l15;
    #pragma unroll
    for (int reg = 0; reg < 4; ++reg) {
      const int m = m0 + wr * 16 + quad * 4 + reg;
      pp.outB[(size_t)m * 128 + n] = bf(acc[j][reg]);
    }
  }
}

// ---------------------------------------------------------------------------
// Fused Wo + residual + LN2 + FFN1 + gelu + FFN2 + residual [+ next LN1].
// 32-row tile, entire chain row-local. LN2 output reuses As; FFN2 residual
// (post-Wo X) stays in registers — no intermediate X/xn global round-trip.
// ---------------------------------------------------------------------------
struct WofnP { const u16* A; const u16* WoT; const float* bo; const float* res;
               const float* g2; const float* b2l;
               const u16* W1t; const float* b1;
               const u16* W2t; const float* b2;
               float* outF; u16* outB; const float* gn; const float* bn; };
struct WofnArgs { WofnP p[2]; int ln; };

__global__ __launch_bounds__(256) void wofn_k(WofnArgs a) {
  const WofnP pp = a.p[blockIdx.y];
  const int m0 = blockIdx.x * 32;
  __shared__ __align__(16) u16 As[32][136];    // ob tile, then LN2 output
  __shared__ __align__(16) u16 Bs[128][136];
  __shared__ __align__(16) u16 Hs[32][264];
  __shared__ float2 stats[32][2];
  const int tid  = threadIdx.x;
  const int w    = tid >> 6;
  const int lane = tid & 63;
  const int l15  = lane & 15;
  const int quad = lane >> 4;
  const int wr = w & 1, wc = w >> 1;

  // ---- stage ob + WoT, Wo GEMM ----
  #pragma unroll
  for (int t = tid; t < 512; t += 256) {
    const int r = t >> 4, g8 = (t & 15) << 3;
    *(short8*)&As[r][g8] = *(const short8*)(pp.A + (size_t)(m0 + r) * 128 + g8);
  }
  #pragma unroll
  for (int t = tid; t < 2048; t += 256) {
    const int r = t >> 4, g8 = (t & 15) << 3;
    *(short8*)&Bs[r][g8] = *(const short8*)(pp.WoT + (size_t)r * 128 + g8);
  }
  __syncthreads();
  f32x4 acc[4];
  #pragma unroll
  for (int j = 0; j < 4; ++j) acc[j] = {0.f, 0.f, 0.f, 0.f};
  #pragma unroll
  for (int ks = 0; ks < 4; ++ks) {
    const short8 ar = *(const short8*)&As[wr * 16 + l15][ks * 32 + quad * 8];
    #pragma unroll
    for (int j = 0; j < 4; ++j) {
      const short8 br = *(const short8*)&Bs[wc * 64 + j * 16 + l15][ks * 32 + quad * 8];
      acc[j] = __builtin_amdgcn_mfma_f32_16x16x32_bf16(ar, br, acc[j], 0, 0, 0);
    }
  }

  // ---- x = Wo-out + bias + residual (keep in registers) ----
  float xv[4][4];
  #pragma unroll
  for (int j = 0; j < 4; ++j) {
    const int n = wc * 64 + j * 16 + l15;
    const float bias_v = pp.bo[n];
    #pragma unroll
    for (int reg = 0; reg < 4; ++reg) {
      const int m = m0 + wr * 16 + quad * 4 + reg;
      xv[j][reg] = acc[j][reg] + bias_v + pp.res[(size_t)m * 128 + n];
    }
  }

  // ---- LN2 -> normalized bf16 into As ----
  #pragma unroll
  for (int reg = 0; reg < 4; ++reg) {
    float s = 0.f, q = 0.f;
    #pragma unroll
    for (int j = 0; j < 4; ++j) { const float v = xv[j][reg]; s += v; q += v * v; }
    #pragma unroll
    for (int off = 8; off >= 1; off >>= 1) {
      s += __shfl_xor(s, off, 16);
      q += __shfl_xor(q, off, 16);
    }
    if (l15 == 0) stats[wr * 16 + quad * 4 + reg][wc] = make_float2(s, q);
  }
  __syncthreads();
  #pragma unroll
  for (int reg = 0; reg < 4; ++reg) {
    const int mloc = wr * 16 + quad * 4 + reg;
    const float2 s0 = stats[mloc][0], s1 = stats[mloc][1];
    const float mean = (s0.x + s1.x) * (1.0f / 128.f);
    const float var  = (s0.y + s1.y) * (1.0f / 128.f) - mean * mean;
    const float r    = rsqrtf(var + 1e-5f);
    #pragma unroll
    for (int j = 0; j < 4; ++j) {
      const int n = wc * 64 + j * 16 + l15;
      As[mloc][n] = bf((xv[j][reg] - mean) * r * pp.g2[n] + pp.b2l[n]);
    }
  }
  __syncthreads();   // As (LN2 out) visible; Bs free

  // ---- FFN1: h = gelu(xn@W1+b1) in LDS, two 128-col halves ----
  for (int nh = 0; nh < 2; ++nh) {
    #pragma unroll
    for (int t = tid; t < 2048; t += 256) {
      const int r = t >> 4, g8 = (t & 15) << 3;
      *(short8*)&Bs[r][g8] = *(const short8*)(pp.W1t + (size_t)(nh * 128 + r) * 128 + g8);
    }
    __syncthreads();
    f32x4 a1[4];
    #pragma unroll
    for (int j = 0; j < 4; ++j) a1[j] = {0.f, 0.f, 0.f, 0.f};
    #pragma unroll
    for (int ks = 0; ks < 4; ++ks) {
      const short8 ar = *(const short8*)&As[wr * 16 + l15][ks * 32 + quad * 8];
      #pragma unroll
      for (int j = 0; j < 4; ++j) {
        const short8 br = *(const short8*)&Bs[wc * 64 + j * 16 + l15][ks * 32 + quad * 8];
        a1[j] = __builtin_amdgcn_mfma_f32_16x16x32_bf16(ar, br, a1[j], 0, 0, 0);
      }
    }
    #pragma unroll
    for (int j = 0; j < 4; ++j) {
      const int n = wc * 64 + j * 16 + l15;
      const float bias_v = pp.b1[nh * 128 + n];
      #pragma unroll
      for (int reg = 0; reg < 4; ++reg) {
        const int mloc = wr * 16 + quad * 4 + reg;
        Hs[mloc][nh * 128 + n] = bf(gelu_f(a1[j][reg] + bias_v));
      }
    }
    __syncthreads();
  }

  // ---- FFN2: out = h@W2 + b2 + x (x from registers), two K-halves ----
  f32x4 a2[4];
  #pragma unroll
  for (int j = 0; j < 4; ++j) a2[j] = {0.f, 0.f, 0.f, 0.f};
  for (int kh = 0; kh < 2; ++kh) {
    #pragma unroll
    for (int t = tid; t < 2048; t += 256) {
      const int r = t >> 4, g8 = (t & 15) << 3;
      *(short8*)&Bs[r][g8] = *(const short8*)(pp.W2t + (size_t)r * 256 + kh * 128 + g8);
    }
    __syncthreads();
    #pragma unroll
    for (int ks = 0; ks < 4; ++ks) {
      const short8 ar = *(const short8*)&Hs[wr * 16 + l15][kh * 128 + ks * 32 + quad * 8];
      #pragma unroll
      for (int j = 0; j < 4; ++j) {
        const short8 br = *(const short8*)&Bs[wc * 64 + j * 16 + l15][ks * 32 + quad * 8];
        a2[j] = __builtin_amdgcn_mfma_f32_16x16x32_bf16(ar, br, a2[j], 0, 0, 0);
      }
    }
    __syncthreads();
  }

  // ---- epilogue: + b2 + x (reg), fp32 out, optional next-layer LN1 ----
  #pragma unroll
  for (int j = 0; j < 4; ++j) {
    const int n = wc * 64 + j * 16 + l15;
    const float bias_v = pp.b2[n];
    #pragma unroll
    for (int reg = 0; reg < 4; ++reg) {
      const int m = m0 + wr * 16 + quad * 4 + reg;
      const float v = a2[j][reg] + bias_v + xv[j][reg];
      xv[j][reg] = v;
      pp.outF[(size_t)m * 128 + n] = v;
    }
  }
  if (!a.ln) return;
  #pragma unroll
  for (int reg = 0; reg < 4; ++reg) {
    float s = 0.f, q = 0.f;
    #pragma unroll
    for (int j = 0; j < 4; ++j) { const float v = xv[j][reg]; s += v; q += v * v; }
    #pragma unroll
    for (int off = 8; off >= 1; off >>= 1) {
      s += __shfl_xor(s, off, 16);
      q += __shfl_xor(q, off, 16);
    }
    if (l15 == 0) stats[wr * 16 + quad * 4 + reg][wc] = make_float2(s, q);
  }
  __syncthreads();
  #pragma unroll
  for (int reg = 0; reg < 4; ++reg) {
    const int mloc = wr * 16 + quad * 4 + reg;
    const float2 s0 = stats[mloc][0], s1 = stats[mloc][1];
    const float mean = (s0.x + s1.x) * (1.0f / 128.f);
    const float var  = (s0.y + s1.y) * (1.0f / 128.f) - mean * mean;
    const float r    = rsqrtf(var + 1e-5f);
    #pragma unroll
    for (int j = 0; j < 4; ++j) {
      const int n = wc * 64 + j * 16 + l15;
      pp.outB[(size_t)(m0 + mloc) * 128 + n] =
          bf((xv[j][reg] - mean) * r * pp.gn[n] + pp.bn[n]);
    }
  }
}

// ---------------------------------------------------------------------------
// MFMA flash attention. S^T orientation (mfma(kb, qa)): lane's 4 regs are 4
// consecutive keys at one query => packed b64 P-writes; scalar denominator.
// V pre-transposed by QKV GEMM => staging is pure b128 copy. 64-key dbuf.
// ---------------------------------------------------------------------------
__global__ __launch_bounds__(256) void attn_k(const u16* __restrict__ qx,
                                              const u16* __restrict__ kx,
                                              const u16* __restrict__ qy,
                                              const u16* __restrict__ ky,
                                              const u16* __restrict__ vtx,
                                              const u16* __restrict__ vty,
                                              u16* __restrict__ o1,
                                              u16* __restrict__ o2) {
  const int t0 = blockIdx.x * 64;
  const int bh = blockIdx.y;
  const int b = bh >> 3, h = bh & 7;
  const size_t base = (size_t)b * TT * DDIM + h * DHH;

  __shared__ __align__(16) u16 Ks[2][64][40];
  __shared__ __align__(16) u16 Vt[2][32][72];
  __shared__ __align__(16) u16 Ps[64][72];

  const int tid  = threadIdx.x;
  const int w    = tid >> 6;
  const int lane = tid & 63;
  const int l15  = lane & 15;
  const int quad = lane >> 4;

  const u16* qp = (quad < 2) ? qx : qy;
  const int dq = (quad & 1) * 8;
  const short8 qa = *(const short8*)(qp + base + (size_t)(t0 + w * 16 + l15) * DDIM + dq);

  f32x4 Of0 = {0.f, 0.f, 0.f, 0.f};
  f32x4 Of1 = {0.f, 0.f, 0.f, 0.f};
  float l_i = 0.f;

  const int ks_s = tid >> 2, ks_c = tid & 3;
  const u16* ks_p = (ks_c < 2) ? kx : ky;
  const int ks_d8 = (ks_c & 1) * 8;
  const int ks_col = (ks_c < 2 ? 0 : 16) + ks_d8;

  const int vs_c = tid >> 3;
  const int vs_s8 = (tid & 7) * 8;
  const u16* vs_row = (vs_c < 16) ? (vtx + (((size_t)bh * 16 + vs_c) << 10))
                                  : (vty + (((size_t)bh * 16 + (vs_c - 16)) << 10));

  #define STAGE(kt, buf)                                                          \
    do {                                                                          \
      const int s0_ = (kt) * 64;                                                  \
      *(short8*)&Ks[buf][ks_s][ks_col] =                                          \
          *(const short8*)(ks_p + base + (size_t)(s0_ + ks_s) * DDIM + ks_d8);    \
      *(short8*)&Vt[buf][vs_c][vs_s8] = *(const short8*)(vs_row + s0_ + vs_s8);   \
    } while (0)

  STAGE(0, 0);

  for (int kt = 0; kt < TT / 64; ++kt) {
    const int buf = kt & 1;
    __syncthreads();
    if (kt + 1 < TT / 64) STAGE(kt + 1, buf ^ 1);

    f32x4 Sf[4];
    #pragma unroll
    for (int t = 0; t < 4; ++t) {
      short8 kb = *(const short8*)&Ks[buf][t * 16 + l15][quad * 8];
      f32x4 z = {0.f, 0.f, 0.f, 0.f};
      Sf[t] = __builtin_amdgcn_mfma_f32_16x16x32_bf16(kb, qa, z, 0, 0, 0);
    }

    #pragma unroll
    for (int t = 0; t < 4; ++t) {
      const float p0 = exp2f(Sf[t][0] * 0.18033688011112042f);
      const float p1 = exp2f(Sf[t][1] * 0.18033688011112042f);
      const float p2 = exp2f(Sf[t][2] * 0.18033688011112042f);
      const float p3 = exp2f(Sf[t][3] * 0.18033688011112042f);
      l_i += p0 + p1 + p2 + p3;
      ushort4 pk;
      pk.x = bft(p0); pk.y = bft(p1); pk.z = bft(p2); pk.w = bft(p3);
      *(ushort4*)&Ps[w * 16 + l15][t * 16 + quad * 4] = pk;
    }

    #pragma unroll
    for (int sh = 0; sh < 2; ++sh) {
      short8 pa  = *(const short8*)&Ps[w * 16 + l15][sh * 32 + quad * 8];
      short8 vb0 = *(const short8*)&Vt[buf][l15][sh * 32 + quad * 8];
      short8 vb1 = *(const short8*)&Vt[buf][16 + l15][sh * 32 + quad * 8];
      Of0 = __builtin_amdgcn_mfma_f32_16x16x32_bf16(pa, vb0, Of0, 0, 0, 0);
      Of1 = __builtin_amdgcn_mfma_f32_16x16x32_bf16(pa, vb1, Of1, 0, 0, 0);
    }
  }
  #undef STAGE

  l_i += __shfl_xor(l_i, 16);
  l_i += __shfl_xor(l_i, 32);
  #pragma unroll
  for (int reg = 0; reg < 4; ++reg) {
    const float lq = __shfl(l_i, quad * 4 + reg, 16);
    const float inv = 1.0f / lq;
    const size_t r = base + (size_t)(t0 + w * 16 + quad * 4 + reg) * DDIM + l15;
    o1[r] = bf(Of0[reg] * inv);
    o2[r] = bf(Of1[reg] * inv);
  }
}

// ---------------------------------------------------------------------------
extern "C" void kernel_launch(void* const* d_in, const int* in_sizes, int n_in,
                              void* d_out, int out_size, void* d_ws, size_t ws_size,
                              hipStream_t stream) {
  const float* x_in  = (const float*)d_in[0];
  const float* y_in  = (const float*)d_in[1];
  const float* Wq    = (const float*)d_in[2];
  const float* Wk    = (const float*)d_in[3];
  const float* Wv    = (const float*)d_in[4];
  const float* Wox   = (const float*)d_in[5];
  const float* box   = (const float*)d_in[6];
  const float* Woy   = (const float*)d_in[7];
  const float* boy   = (const float*)d_in[8];
  const float* ln1xg = (const float*)d_in[9];
  const float* ln1xb = (const float*)d_in[10];
  const float* ln1yg = (const float*)d_in[11];
  const float* ln1yb = (const float*)d_in[12];
  const float* ln2xg = (const float*)d_in[13];
  const float* ln2xb = (const float*)d_in[14];
  const float* ln2yg = (const float*)d_in[15];
  const float* ln2yb = (const float*)d_in[16];
  const float* fxw1  = (const float*)d_in[17];
  const float* fxb1  = (const float*)d_in[18];
  const float* fxw2  = (const float*)d_in[19];
  const float* fxb2  = (const float*)d_in[20];
  const float* fyw1  = (const float*)d_in[21];
  const float* fyb1  = (const float*)d_in[22];
  const float* fyw2  = (const float*)d_in[23];
  const float* fyb2  = (const float*)d_in[24];

  const size_t S = (size_t)BT * DDIM;  // 1,048,576 elems
  float* X = (float*)d_out;
  float* Y = X + S;

  char* wsb = (char*)d_ws;
  auto carve = [&](size_t bytes) { char* p = wsb; wsb += (bytes + 255) & ~(size_t)255; return p; };
  u16* xn  = (u16*)carve(S * 2);
  u16* yn  = (u16*)carve(S * 2);
  u16* qx  = (u16*)carve(S * 2);
  u16* kx  = (u16*)carve(S * 2);
  u16* qy  = (u16*)carve(S * 2);
  u16* ky  = (u16*)carve(S * 2);
  u16* vxT = (u16*)carve(S * 2);   // vT[(b*8+h)*16+c][s]
  u16* vyT = (u16*)carve(S * 2);
  u16* ob1 = (u16*)carve(S * 2);
  u16* ob2 = (u16*)carve(S * 2);
  u16* WqT[2], *WkT[2], *WvT[2], *WoxT[2], *WoyT[2];
  u16* f1xT[2], *f1yT[2], *f2xT[2], *f2yT[2];
  for (int l = 0; l < 2; ++l) {
    WqT[l]  = (u16*)carve(16384 * 2);
    WkT[l]  = (u16*)carve(16384 * 2);
    WvT[l]  = (u16*)carve(16384 * 2);
    WoxT[l] = (u16*)carve(16384 * 2);
    WoyT[l] = (u16*)carve(16384 * 2);
    f1xT[l] = (u16*)carve(32768 * 2);
    f1yT[l] = (u16*)carve(32768 * 2);
    f2xT[l] = (u16*)carve(32768 * 2);
    f2yT[l] = (u16*)carve(32768 * 2);
  }

  // setup: weight prep (104 units) + layer-0 LN1 (4096 units)
  {
    SetupArgs a;
    int pi = 0;
    for (int l = 0; l < 2; ++l) {
      a.prep[pi++] = {Wq  + (size_t)l * 16384, WqT[l]};
      a.prep[pi++] = {Wk  + (size_t)l * 16384, WkT[l]};
      a.prep[pi++] = {Wv  + (size_t)l * 16384, WvT[l]};
      a.prep[pi++] = {Wox + (size_t)l * 16384, WoxT[l]};
      a.prep[pi++] = {Woy + (size_t)l * 16384, WoyT[l]};
    }
    for (int l = 0; l < 2; ++l) {
      a.prep[pi++] = {fxw1 + (size_t)l * 32768, f1xT[l]};
      a.prep[pi++] = {fyw1 + (size_t)l * 32768, f1yT[l]};
    }
    for (int l = 0; l < 2; ++l) {
      a.prep[pi++] = {fxw2 + (size_t)l * 32768, f2xT[l]};
      a.prep[pi++] = {fyw2 + (size_t)l * 32768, f2yT[l]};
    }
    a.x_in = x_in; a.y_in = y_in;
    a.ln1xg = ln1xg; a.ln1xb = ln1xb; a.ln1yg = ln1yg; a.ln1yb = ln1yb;
    a.xn = xn; a.yn = yn;
    setup_k<<<dim3(104 + 4096), 256, 0, stream>>>(a);
  }

  for (int l = 0; l < 2; ++l) {
    const size_t bo  = (size_t)l * DDIM;
    const size_t fbo = (size_t)l * FF;

    // QKV (6-way batched); V ops write transposed
    {
      GemmArgs a = {};
      a.p[0] = {yn, WqT[l], qx, nullptr};
      a.p[1] = {xn, WkT[l], kx, nullptr};
      a.p[2] = {xn, WvT[l], nullptr, vxT};
      a.p[3] = {xn, WqT[l], qy, nullptr};
      a.p[4] = {yn, WkT[l], ky, nullptr};
      a.p[5] = {yn, WvT[l], nullptr, vyT};
      gemmf_k<<<dim3(1, BT / 32, 6), 256, 0, stream>>>(a);
    }
    // fused attention
    attn_k<<<dim3(TT / 64, BB * HH), 256, 0, stream>>>(qx, kx, qy, ky, vxT, vyT, ob1, ob2);
    // fused Wo + res + LN2 + FFN (+ next-layer LN1 for l==0)
    {
      const float* resx = (l == 0) ? x_in : X;
      const float* resy = (l == 0) ? y_in : Y;
      WofnArgs a = {}; a.ln = (l == 0) ? 1 : 0;
      a.p[0] = {ob1, WoxT[l], box + bo, resx, ln2xg + bo, ln2xb + bo,
                f1xT[l], fxb1 + fbo, f2xT[l], fxb2 + bo,
                X, (l == 0) ? xn : nullptr,
                (l == 0) ? ln1xg + DDIM : nullptr, (l == 0) ? ln1xb + DDIM : nullptr};
      a.p[1] = {ob2, WoyT[l], boy + bo, resy, ln2yg + bo, ln2yb + bo,
                f1yT[l], fyb1 + fbo, f2yT[l], fyb2 + bo,
                Y, (l == 0) ? yn : nullptr,
                (l == 0) ? ln1yg + DDIM : nullptr, (l == 0) ? ln1yb + DDIM : nullptr};
      wofn_k<<<dim3(BT / 32, 2), 256, 0, stream>>>(a);
    }
  }
}

// Round 13
// 221.964 us; speedup vs baseline: 4.9962x; 1.0199x over previous
//
#include <hip/hip_runtime.h>
#include <cstddef>

#define BB   8
#define TT   1024
#define DDIM 128
#define HH   8
#define DHH  16
#define FF   256
#define BT   (BB * TT)   // 8192

typedef unsigned short u16;
typedef __attribute__((ext_vector_type(8))) short short8;
typedef __attribute__((ext_vector_type(4))) float f32x4;

__device__ __forceinline__ u16 bf(float x) {
  unsigned u = __builtin_bit_cast(unsigned, x);
  u += 0x7fffu + ((u >> 16) & 1u);   // RTN-even
  return (u16)(u >> 16);
}
__device__ __forceinline__ u16 bft(float x) {           // truncate (P in [0,1])
  return (u16)(__builtin_bit_cast(unsigned, x) >> 16);
}
__device__ __forceinline__ float gelu_f(float x) {
  const float t = x * (0.79788456f + 0.03567740814f * x * x);
  return x / (1.0f + __expf(-2.0f * t));
}

// ---------------------------------------------------------------------------
// QKV tail: As holds 32 normalized bf16 rows; run 3 GEMM passes producing
// q (bf16), k (bf16), vT (transposed: vT[(b*8+h)*16+c][s]). Proven pattern.
// Precondition: As writes happened before call; Bs free.
// ---------------------------------------------------------------------------
__device__ __forceinline__ void qkv_tail(
    const u16* __restrict__ Wq, const u16* __restrict__ Wk, const u16* __restrict__ Wv,
    u16* __restrict__ q_out, u16* __restrict__ k_out, u16* __restrict__ vT_out,
    int m0, u16 (*As)[136], u16 (*Bs)[136]) {
  const int tid = threadIdx.x;
  const int w = tid >> 6, lane = tid & 63, l15 = lane & 15, quad = lane >> 4;
  const int wr = w & 1, wc = w >> 1;
  const u16* Ws[3] = {Wq, Wk, Wv};
  #pragma unroll
  for (int wi = 0; wi < 3; ++wi) {
    #pragma unroll
    for (int t = tid; t < 2048; t += 256) {
      const int r = t >> 4, g8 = (t & 15) << 3;
      *(short8*)&Bs[r][g8] = *(const short8*)(Ws[wi] + (size_t)r * 128 + g8);
    }
    __syncthreads();
    f32x4 acc[4];
    #pragma unroll
    for (int j = 0; j < 4; ++j) acc[j] = {0.f, 0.f, 0.f, 0.f};
    #pragma unroll
    for (int ks = 0; ks < 4; ++ks) {
      const short8 ar = *(const short8*)&As[wr * 16 + l15][ks * 32 + quad * 8];
      #pragma unroll
      for (int j = 0; j < 4; ++j) {
        const short8 br = *(const short8*)&Bs[wc * 64 + j * 16 + l15][ks * 32 + quad * 8];
        acc[j] = __builtin_amdgcn_mfma_f32_16x16x32_bf16(ar, br, acc[j], 0, 0, 0);
      }
    }
    if (wi == 2) {
      const int m_base = m0 + wr * 16 + quad * 4;
      const int bb_ = m_base >> 10, s = m_base & 1023;
      #pragma unroll
      for (int j = 0; j < 4; ++j) {
        const int n = wc * 64 + j * 16 + l15;
        const int h = n >> 4, c = n & 15;
        ushort4 o;
        o.x = bf(acc[j][0]); o.y = bf(acc[j][1]);
        o.z = bf(acc[j][2]); o.w = bf(acc[j][3]);
        *(ushort4*)(vT_out + (((size_t)(bb_ * 8 + h) * 16 + c) << 10) + s) = o;
      }
    } else {
      u16* out = (wi == 0) ? q_out : k_out;
      #pragma unroll
      for (int j = 0; j < 4; ++j) {
        const int n = wc * 64 + j * 16 + l15;
        #pragma unroll
        for (int reg = 0; reg < 4; ++reg) {
          const int m = m0 + wr * 16 + quad * 4 + reg;
          out[(size_t)m * 128 + n] = bf(acc[j][reg]);
        }
      }
    }
    __syncthreads();   // Bs free for next pass
  }
}

// ---------------------------------------------------------------------------
// Weight prep: fp32 (K,N) -> bf16 (N,K)  (transpose + convert), 18 matrices.
// ---------------------------------------------------------------------------
struct PrepP { const float* W; u16* Wt; int K; int N; };
struct PrepArgs { PrepP p[18]; };

__global__ __launch_bounds__(256) void prep_k(PrepArgs a) {
  const PrepP pp = a.p[blockIdx.z];
  const int n0 = blockIdx.x * 64, k0 = blockIdx.y * 64;
  if (n0 >= pp.N || k0 >= pp.K) return;
  __shared__ float tile[64][65];
  const int tid = threadIdx.x;
  #pragma unroll
  for (int t = tid; t < 1024; t += 256) {
    const int kk = t >> 4, nn4 = (t & 15) << 2;
    float4 v = *(const float4*)(pp.W + (size_t)(k0 + kk) * pp.N + n0 + nn4);
    tile[nn4 + 0][kk] = v.x; tile[nn4 + 1][kk] = v.y;
    tile[nn4 + 2][kk] = v.z; tile[nn4 + 3][kk] = v.w;
  }
  __syncthreads();
  #pragma unroll
  for (int t = tid; t < 1024; t += 256) {
    const int nn = t >> 4, kk4 = (t & 15) << 2;
    ushort4 o;
    o.x = bf(tile[nn][kk4 + 0]); o.y = bf(tile[nn][kk4 + 1]);
    o.z = bf(tile[nn][kk4 + 2]); o.w = bf(tile[nn][kk4 + 3]);
    *(ushort4*)(pp.Wt + (size_t)(n0 + nn) * pp.K + k0 + kk4) = o;
  }
}

// ---------------------------------------------------------------------------
// lnqkv_k: layer-0 LN1 (fp32 in, fragment-layout loads) -> As, then QKV tail.
// branch 0 (x rows) -> {qy, kx, vxT}; branch 1 (y rows) -> {qx, ky, vyT}.
// ---------------------------------------------------------------------------
struct LnqkvP { const float* in; const float* g; const float* b;
                const u16* Wq; const u16* Wk; const u16* Wv;
                u16* q_out; u16* k_out; u16* vT_out; };
struct LnqkvArgs { LnqkvP p[2]; };

__global__ __launch_bounds__(256) void lnqkv_k(LnqkvArgs a) {
  const LnqkvP pp = a.p[blockIdx.y];
  const int m0 = blockIdx.x * 32;
  __shared__ __align__(16) u16 As[32][136];
  __shared__ __align__(16) u16 Bs[128][136];
  __shared__ float2 stats[32][2];
  const int tid  = threadIdx.x;
  const int w    = tid >> 6;
  const int lane = tid & 63;
  const int l15  = lane & 15;
  const int quad = lane >> 4;
  const int wr = w & 1, wc = w >> 1;

  float xv[4][4];
  #pragma unroll
  for (int j = 0; j < 4; ++j) {
    const int n = wc * 64 + j * 16 + l15;
    #pragma unroll
    for (int reg = 0; reg < 4; ++reg) {
      const int m = m0 + wr * 16 + quad * 4 + reg;
      xv[j][reg] = pp.in[(size_t)m * 128 + n];
    }
  }
  #pragma unroll
  for (int reg = 0; reg < 4; ++reg) {
    float s = 0.f, q = 0.f;
    #pragma unroll
    for (int j = 0; j < 4; ++j) { const float v = xv[j][reg]; s += v; q += v * v; }
    #pragma unroll
    for (int off = 8; off >= 1; off >>= 1) {
      s += __shfl_xor(s, off, 16);
      q += __shfl_xor(q, off, 16);
    }
    if (l15 == 0) stats[wr * 16 + quad * 4 + reg][wc] = make_float2(s, q);
  }
  __syncthreads();
  #pragma unroll
  for (int reg = 0; reg < 4; ++reg) {
    const int mloc = wr * 16 + quad * 4 + reg;
    const float2 s0 = stats[mloc][0], s1 = stats[mloc][1];
    const float mean = (s0.x + s1.x) * (1.0f / 128.f);
    const float var  = (s0.y + s1.y) * (1.0f / 128.f) - mean * mean;
    const float r    = rsqrtf(var + 1e-5f);
    #pragma unroll
    for (int j = 0; j < 4; ++j) {
      const int n = wc * 64 + j * 16 + l15;
      As[mloc][n] = bf((xv[j][reg] - mean) * r * pp.g[n] + pp.b[n]);
    }
  }
  qkv_tail(pp.Wq, pp.Wk, pp.Wv, pp.q_out, pp.k_out, pp.vT_out, m0, As, Bs);
}

// ---------------------------------------------------------------------------
// Fused Wo + residual + LN2 + FFN1 + gelu + FFN2 + residual
// [+ next-layer LN1 + next-layer QKV tail when ln==1].
// ---------------------------------------------------------------------------
struct WofnP { const u16* A; const u16* WoT; const float* bo; const float* res;
               const float* g2; const float* b2l;
               const u16* W1t; const float* b1;
               const u16* W2t; const float* b2;
               float* outF;
               const float* gn; const float* bn;                 // next LN1
               const u16* nWq; const u16* nWk; const u16* nWv;   // next QKV
               u16* q_out; u16* k_out; u16* vT_out; };
struct WofnArgs { WofnP p[2]; int ln; };

__global__ __launch_bounds__(256) void wofn_k(WofnArgs a) {
  const WofnP pp = a.p[blockIdx.y];
  const int m0 = blockIdx.x * 32;
  __shared__ __align__(16) u16 As[32][136];
  __shared__ __align__(16) u16 Bs[128][136];
  __shared__ __align__(16) u16 Hs[32][264];
  __shared__ float2 stats[32][2];
  const int tid  = threadIdx.x;
  const int w    = tid >> 6;
  const int lane = tid & 63;
  const int l15  = lane & 15;
  const int quad = lane >> 4;
  const int wr = w & 1, wc = w >> 1;

  // ---- stage ob + WoT, Wo GEMM ----
  #pragma unroll
  for (int t = tid; t < 512; t += 256) {
    const int r = t >> 4, g8 = (t & 15) << 3;
    *(short8*)&As[r][g8] = *(const short8*)(pp.A + (size_t)(m0 + r) * 128 + g8);
  }
  #pragma unroll
  for (int t = tid; t < 2048; t += 256) {
    const int r = t >> 4, g8 = (t & 15) << 3;
    *(short8*)&Bs[r][g8] = *(const short8*)(pp.WoT + (size_t)r * 128 + g8);
  }
  __syncthreads();
  f32x4 acc[4];
  #pragma unroll
  for (int j = 0; j < 4; ++j) acc[j] = {0.f, 0.f, 0.f, 0.f};
  #pragma unroll
  for (int ks = 0; ks < 4; ++ks) {
    const short8 ar = *(const short8*)&As[wr * 16 + l15][ks * 32 + quad * 8];
    #pragma unroll
    for (int j = 0; j < 4; ++j) {
      const short8 br = *(const short8*)&Bs[wc * 64 + j * 16 + l15][ks * 32 + quad * 8];
      acc[j] = __builtin_amdgcn_mfma_f32_16x16x32_bf16(ar, br, acc[j], 0, 0, 0);
    }
  }

  // ---- x = Wo-out + bias + residual (registers) ----
  float xv[4][4];
  #pragma unroll
  for (int j = 0; j < 4; ++j) {
    const int n = wc * 64 + j * 16 + l15;
    const float bias_v = pp.bo[n];
    #pragma unroll
    for (int reg = 0; reg < 4; ++reg) {
      const int m = m0 + wr * 16 + quad * 4 + reg;
      xv[j][reg] = acc[j][reg] + bias_v + pp.res[(size_t)m * 128 + n];
    }
  }

  // ---- LN2 -> normalized bf16 into As ----
  #pragma unroll
  for (int reg = 0; reg < 4; ++reg) {
    float s = 0.f, q = 0.f;
    #pragma unroll
    for (int j = 0; j < 4; ++j) { const float v = xv[j][reg]; s += v; q += v * v; }
    #pragma unroll
    for (int off = 8; off >= 1; off >>= 1) {
      s += __shfl_xor(s, off, 16);
      q += __shfl_xor(q, off, 16);
    }
    if (l15 == 0) stats[wr * 16 + quad * 4 + reg][wc] = make_float2(s, q);
  }
  __syncthreads();
  #pragma unroll
  for (int reg = 0; reg < 4; ++reg) {
    const int mloc = wr * 16 + quad * 4 + reg;
    const float2 s0 = stats[mloc][0], s1 = stats[mloc][1];
    const float mean = (s0.x + s1.x) * (1.0f / 128.f);
    const float var  = (s0.y + s1.y) * (1.0f / 128.f) - mean * mean;
    const float r    = rsqrtf(var + 1e-5f);
    #pragma unroll
    for (int j = 0; j < 4; ++j) {
      const int n = wc * 64 + j * 16 + l15;
      As[mloc][n] = bf((xv[j][reg] - mean) * r * pp.g2[n] + pp.b2l[n]);
    }
  }
  __syncthreads();   // As (LN2 out) visible; Bs free

  // ---- FFN1: h = gelu(xn@W1+b1) in LDS, two 128-col halves ----
  for (int nh = 0; nh < 2; ++nh) {
    #pragma unroll
    for (int t = tid; t < 2048; t += 256) {
      const int r = t >> 4, g8 = (t & 15) << 3;
      *(short8*)&Bs[r][g8] = *(const short8*)(pp.W1t + (size_t)(nh * 128 + r) * 128 + g8);
    }
    __syncthreads();
    f32x4 a1[4];
    #pragma unroll
    for (int j = 0; j < 4; ++j) a1[j] = {0.f, 0.f, 0.f, 0.f};
    #pragma unroll
    for (int ks = 0; ks < 4; ++ks) {
      const short8 ar = *(const short8*)&As[wr * 16 + l15][ks * 32 + quad * 8];
      #pragma unroll
      for (int j = 0; j < 4; ++j) {
        const short8 br = *(const short8*)&Bs[wc * 64 + j * 16 + l15][ks * 32 + quad * 8];
        a1[j] = __builtin_amdgcn_mfma_f32_16x16x32_bf16(ar, br, a1[j], 0, 0, 0);
      }
    }
    #pragma unroll
    for (int j = 0; j < 4; ++j) {
      const int n = wc * 64 + j * 16 + l15;
      const float bias_v = pp.b1[nh * 128 + n];
      #pragma unroll
      for (int reg = 0; reg < 4; ++reg) {
        const int mloc = wr * 16 + quad * 4 + reg;
        Hs[mloc][nh * 128 + n] = bf(gelu_f(a1[j][reg] + bias_v));
      }
    }
    __syncthreads();
  }

  // ---- FFN2: out = h@W2 + b2 + x (registers), two K-halves ----
  f32x4 a2[4];
  #pragma unroll
  for (int j = 0; j < 4; ++j) a2[j] = {0.f, 0.f, 0.f, 0.f};
  for (int kh = 0; kh < 2; ++kh) {
    #pragma unroll
    for (int t = tid; t < 2048; t += 256) {
      const int r = t >> 4, g8 = (t & 15) << 3;
      *(short8*)&Bs[r][g8] = *(const short8*)(pp.W2t + (size_t)r * 256 + kh * 128 + g8);
    }
    __syncthreads();
    #pragma unroll
    for (int ks = 0; ks < 4; ++ks) {
      const short8 ar = *(const short8*)&Hs[wr * 16 + l15][kh * 128 + ks * 32 + quad * 8];
      #pragma unroll
      for (int j = 0; j < 4; ++j) {
        const short8 br = *(const short8*)&Bs[wc * 64 + j * 16 + l15][ks * 32 + quad * 8];
        a2[j] = __builtin_amdgcn_mfma_f32_16x16x32_bf16(ar, br, a2[j], 0, 0, 0);
      }
    }
    __syncthreads();
  }

  // ---- epilogue: + b2 + x (reg), fp32 out ----
  #pragma unroll
  for (int j = 0; j < 4; ++j) {
    const int n = wc * 64 + j * 16 + l15;
    const float bias_v = pp.b2[n];
    #pragma unroll
    for (int reg = 0; reg < 4; ++reg) {
      const int m = m0 + wr * 16 + quad * 4 + reg;
      const float v = a2[j][reg] + bias_v + xv[j][reg];
      xv[j][reg] = v;
      pp.outF[(size_t)m * 128 + n] = v;
    }
  }
  if (!a.ln) return;

  // ---- next-layer LN1 -> As, then next-layer QKV tail ----
  #pragma unroll
  for (int reg = 0; reg < 4; ++reg) {
    float s = 0.f, q = 0.f;
    #pragma unroll
    for (int j = 0; j < 4; ++j) { const float v = xv[j][reg]; s += v; q += v * v; }
    #pragma unroll
    for (int off = 8; off >= 1; off >>= 1) {
      s += __shfl_xor(s, off, 16);
      q += __shfl_xor(q, off, 16);
    }
    if (l15 == 0) stats[wr * 16 + quad * 4 + reg][wc] = make_float2(s, q);
  }
  __syncthreads();
  #pragma unroll
  for (int reg = 0; reg < 4; ++reg) {
    const int mloc = wr * 16 + quad * 4 + reg;
    const float2 s0 = stats[mloc][0], s1 = stats[mloc][1];
    const float mean = (s0.x + s1.x) * (1.0f / 128.f);
    const float var  = (s0.y + s1.y) * (1.0f / 128.f) - mean * mean;
    const float r    = rsqrtf(var + 1e-5f);
    #pragma unroll
    for (int j = 0; j < 4; ++j) {
      const int n = wc * 64 + j * 16 + l15;
      As[mloc][n] = bf((xv[j][reg] - mean) * r * pp.gn[n] + pp.bn[n]);
    }
  }
  qkv_tail(pp.nWq, pp.nWk, pp.nWv, pp.q_out, pp.k_out, pp.vT_out, m0, As, Bs);
}

// ---------------------------------------------------------------------------
// MFMA flash attention. S^T orientation (mfma(kb, qa)): lane's 4 regs are 4
// consecutive keys at one query => packed b64 P-writes; scalar denominator.
// V pre-transposed (vT[bh*16+c][s]) => staging is pure b128 copy. 64-key dbuf.
// ---------------------------------------------------------------------------
__global__ __launch_bounds__(256) void attn_k(const u16* __restrict__ qx,
                                              const u16* __restrict__ kx,
                                              const u16* __restrict__ qy,
                                              const u16* __restrict__ ky,
                                              const u16* __restrict__ vtx,
                                              const u16* __restrict__ vty,
                                              u16* __restrict__ o1,
                                              u16* __restrict__ o2) {
  const int t0 = blockIdx.x * 64;
  const int bh = blockIdx.y;
  const int b = bh >> 3, h = bh & 7;
  const size_t base = (size_t)b * TT * DDIM + h * DHH;

  __shared__ __align__(16) u16 Ks[2][64][40];
  __shared__ __align__(16) u16 Vt[2][32][72];
  __shared__ __align__(16) u16 Ps[64][72];

  const int tid  = threadIdx.x;
  const int w    = tid >> 6;
  const int lane = tid & 63;
  const int l15  = lane & 15;
  const int quad = lane >> 4;

  const u16* qp = (quad < 2) ? qx : qy;
  const int dq = (quad & 1) * 8;
  const short8 qa = *(const short8*)(qp + base + (size_t)(t0 + w * 16 + l15) * DDIM + dq);

  f32x4 Of0 = {0.f, 0.f, 0.f, 0.f};
  f32x4 Of1 = {0.f, 0.f, 0.f, 0.f};
  float l_i = 0.f;

  const int ks_s = tid >> 2, ks_c = tid & 3;
  const u16* ks_p = (ks_c < 2) ? kx : ky;
  const int ks_d8 = (ks_c & 1) * 8;
  const int ks_col = (ks_c < 2 ? 0 : 16) + ks_d8;

  const int vs_c = tid >> 3;
  const int vs_s8 = (tid & 7) * 8;
  const u16* vs_row = (vs_c < 16) ? (vtx + (((size_t)bh * 16 + vs_c) << 10))
                                  : (vty + (((size_t)bh * 16 + (vs_c - 16)) << 10));

  #define STAGE(kt, buf)                                                          \
    do {                                                                          \
      const int s0_ = (kt) * 64;                                                  \
      *(short8*)&Ks[buf][ks_s][ks_col] =                                          \
          *(const short8*)(ks_p + base + (size_t)(s0_ + ks_s) * DDIM + ks_d8);    \
      *(short8*)&Vt[buf][vs_c][vs_s8] = *(const short8*)(vs_row + s0_ + vs_s8);   \
    } while (0)

  STAGE(0, 0);

  for (int kt = 0; kt < TT / 64; ++kt) {
    const int buf = kt & 1;
    __syncthreads();
    if (kt + 1 < TT / 64) STAGE(kt + 1, buf ^ 1);

    f32x4 Sf[4];
    #pragma unroll
    for (int t = 0; t < 4; ++t) {
      short8 kb = *(const short8*)&Ks[buf][t * 16 + l15][quad * 8];
      f32x4 z = {0.f, 0.f, 0.f, 0.f};
      Sf[t] = __builtin_amdgcn_mfma_f32_16x16x32_bf16(kb, qa, z, 0, 0, 0);
    }

    #pragma unroll
    for (int t = 0; t < 4; ++t) {
      const float p0 = exp2f(Sf[t][0] * 0.18033688011112042f);
      const float p1 = exp2f(Sf[t][1] * 0.18033688011112042f);
      const float p2 = exp2f(Sf[t][2] * 0.18033688011112042f);
      const float p3 = exp2f(Sf[t][3] * 0.18033688011112042f);
      l_i += p0 + p1 + p2 + p3;
      ushort4 pk;
      pk.x = bft(p0); pk.y = bft(p1); pk.z = bft(p2); pk.w = bft(p3);
      *(ushort4*)&Ps[w * 16 + l15][t * 16 + quad * 4] = pk;
    }

    #pragma unroll
    for (int sh = 0; sh < 2; ++sh) {
      short8 pa  = *(const short8*)&Ps[w * 16 + l15][sh * 32 + quad * 8];
      short8 vb0 = *(const short8*)&Vt[buf][l15][sh * 32 + quad * 8];
      short8 vb1 = *(const short8*)&Vt[buf][16 + l15][sh * 32 + quad * 8];
      Of0 = __builtin_amdgcn_mfma_f32_16x16x32_bf16(pa, vb0, Of0, 0, 0, 0);
      Of1 = __builtin_amdgcn_mfma_f32_16x16x32_bf16(pa, vb1, Of1, 0, 0, 0);
    }
  }
  #undef STAGE

  l_i += __shfl_xor(l_i, 16);
  l_i += __shfl_xor(l_i, 32);
  #pragma unroll
  for (int reg = 0; reg < 4; ++reg) {
    const float lq = __shfl(l_i, quad * 4 + reg, 16);
    const float inv = 1.0f / lq;
    const size_t r = base + (size_t)(t0 + w * 16 + quad * 4 + reg) * DDIM + l15;
    o1[r] = bf(Of0[reg] * inv);
    o2[r] = bf(Of1[reg] * inv);
  }
}

// ---------------------------------------------------------------------------
extern "C" void kernel_launch(void* const* d_in, const int* in_sizes, int n_in,
                              void* d_out, int out_size, void* d_ws, size_t ws_size,
                              hipStream_t stream) {
  const float* x_in  = (const float*)d_in[0];
  const float* y_in  = (const float*)d_in[1];
  const float* Wq    = (const float*)d_in[2];
  const float* Wk    = (const float*)d_in[3];
  const float* Wv    = (const float*)d_in[4];
  const float* Wox   = (const float*)d_in[5];
  const float* box   = (const float*)d_in[6];
  const float* Woy   = (const float*)d_in[7];
  const float* boy   = (const float*)d_in[8];
  const float* ln1xg = (const float*)d_in[9];
  const float* ln1xb = (const float*)d_in[10];
  const float* ln1yg = (const float*)d_in[11];
  const float* ln1yb = (const float*)d_in[12];
  const float* ln2xg = (const float*)d_in[13];
  const float* ln2xb = (const float*)d_in[14];
  const float* ln2yg = (const float*)d_in[15];
  const float* ln2yb = (const float*)d_in[16];
  const float* fxw1  = (const float*)d_in[17];
  const float* fxb1  = (const float*)d_in[18];
  const float* fxw2  = (const float*)d_in[19];
  const float* fxb2  = (const float*)d_in[20];
  const float* fyw1  = (const float*)d_in[21];
  const float* fyb1  = (const float*)d_in[22];
  const float* fyw2  = (const float*)d_in[23];
  const float* fyb2  = (const float*)d_in[24];

  const size_t S = (size_t)BT * DDIM;  // 1,048,576 elems
  float* X = (float*)d_out;
  float* Y = X + S;

  char* wsb = (char*)d_ws;
  auto carve = [&](size_t bytes) { char* p = wsb; wsb += (bytes + 255) & ~(size_t)255; return p; };
  u16* qx  = (u16*)carve(S * 2);
  u16* kx  = (u16*)carve(S * 2);
  u16* qy  = (u16*)carve(S * 2);
  u16* ky  = (u16*)carve(S * 2);
  u16* vxT = (u16*)carve(S * 2);   // vT[(b*8+h)*16+c][s]
  u16* vyT = (u16*)carve(S * 2);
  u16* ob1 = (u16*)carve(S * 2);
  u16* ob2 = (u16*)carve(S * 2);
  u16* WqT[2], *WkT[2], *WvT[2], *WoxT[2], *WoyT[2];
  u16* f1xT[2], *f1yT[2], *f2xT[2], *f2yT[2];
  for (int l = 0; l < 2; ++l) {
    WqT[l]  = (u16*)carve(16384 * 2);
    WkT[l]  = (u16*)carve(16384 * 2);
    WvT[l]  = (u16*)carve(16384 * 2);
    WoxT[l] = (u16*)carve(16384 * 2);
    WoyT[l] = (u16*)carve(16384 * 2);
    f1xT[l] = (u16*)carve(32768 * 2);
    f1yT[l] = (u16*)carve(32768 * 2);
    f2xT[l] = (u16*)carve(32768 * 2);
    f2yT[l] = (u16*)carve(32768 * 2);
  }

  // weight transpose+convert (all layers, one kernel)
  {
    PrepArgs a;
    int idx = 0;
    for (int l = 0; l < 2; ++l) {
      a.p[idx++] = {Wq  + (size_t)l * 16384, WqT[l],  128, 128};
      a.p[idx++] = {Wk  + (size_t)l * 16384, WkT[l],  128, 128};
      a.p[idx++] = {Wv  + (size_t)l * 16384, WvT[l],  128, 128};
      a.p[idx++] = {Wox + (size_t)l * 16384, WoxT[l], 128, 128};
      a.p[idx++] = {Woy + (size_t)l * 16384, WoyT[l], 128, 128};
      a.p[idx++] = {fxw1 + (size_t)l * 32768, f1xT[l], 128, 256};
      a.p[idx++] = {fyw1 + (size_t)l * 32768, f1yT[l], 128, 256};
      a.p[idx++] = {fxw2 + (size_t)l * 32768, f2xT[l], 256, 128};
      a.p[idx++] = {fyw2 + (size_t)l * 32768, f2yT[l], 256, 128};
    }
    prep_k<<<dim3(4, 4, 18), 256, 0, stream>>>(a);
  }

  // layer-0 LN1 + QKV (fused)
  {
    LnqkvArgs a;
    a.p[0] = {x_in, ln1xg, ln1xb, WqT[0], WkT[0], WvT[0], qy, kx, vxT};
    a.p[1] = {y_in, ln1yg, ln1yb, WqT[0], WkT[0], WvT[0], qx, ky, vyT};
    lnqkv_k<<<dim3(BT / 32, 2), 256, 0, stream>>>(a);
  }

  for (int l = 0; l < 2; ++l) {
    const size_t bo  = (size_t)l * DDIM;
    const size_t fbo = (size_t)l * FF;

    // fused attention
    attn_k<<<dim3(TT / 64, BB * HH), 256, 0, stream>>>(qx, kx, qy, ky, vxT, vyT, ob1, ob2);

    // fused Wo + res + LN2 + FFN (+ next-layer LN1 + QKV for l==0)
    {
      const float* resx = (l == 0) ? x_in : X;
      const float* resy = (l == 0) ? y_in : Y;
      WofnArgs a = {}; a.ln = (l == 0) ? 1 : 0;
      a.p[0] = {ob1, WoxT[l], box + bo, resx, ln2xg + bo, ln2xb + bo,
                f1xT[l], fxb1 + fbo, f2xT[l], fxb2 + bo, X,
                (l == 0) ? ln1xg + DDIM : nullptr, (l == 0) ? ln1xb + DDIM : nullptr,
                (l == 0) ? WqT[1] : nullptr, (l == 0) ? WkT[1] : nullptr,
                (l == 0) ? WvT[1] : nullptr,
                (l == 0) ? qy : nullptr, (l == 0) ? kx : nullptr,
                (l == 0) ? vxT : nullptr};
      a.p[1] = {ob2, WoyT[l], boy + bo, resy, ln2yg + bo, ln2yb + bo,
                f1yT[l], fyb1 + fbo, f2yT[l], fyb2 + bo, Y,
                (l == 0) ? ln1yg + DDIM : nullptr, (l == 0) ? ln1yb + DDIM : nullptr,
                (l == 0) ? WqT[1] : nullptr, (l == 0) ? WkT[1] : nullptr,
                (l == 0) ? WvT[1] : nullptr,
                (l == 0) ? qx : nullptr, (l == 0) ? ky : nullptr,
                (l == 0) ? vyT : nullptr};
      wofn_k<<<dim3(BT / 32, 2), 256, 0, stream>>>(a);
    }
  }
}